// Round 4
// baseline (688.000 us; speedup 1.0000x reference)
//
#include <hip/hip_runtime.h>
#include <hip/hip_bf16.h>
#include <math.h>

constexpr int SEQ = 256;
constexpr int DIM = 768;
constexpr int NH  = 8;
constexpr int HD  = 96;

typedef __attribute__((ext_vector_type(8))) short short8;
typedef __attribute__((ext_vector_type(4))) float f32x4;
using bf16 = __hip_bfloat16;

#define ASYNC_COPY16(gptr, lptr) \
  __builtin_amdgcn_global_load_lds((const __attribute__((address_space(1))) void*)(gptr), \
                                   (__attribute__((address_space(3))) void*)(lptr), 16, 0, 0)

// ---------------------------------------------------------------------------
// f32 tiled GEMM (biasT only now): C[m,n] = acc*scale + rtab[rp[n*256+m]*8+hz]
// C written as bf16.
// ---------------------------------------------------------------------------
__global__ __launch_bounds__(256) void gemm_kernel(
    const float* __restrict__ A, int lda, long aoz,
    const float* __restrict__ W, int ldw, long woz,
    const float* __restrict__ bias, long boz,
    bf16* __restrict__ C, int ldc, long coz,
    int M, int N, int K, float scale,
    const int* __restrict__ rp, const float* __restrict__ rtab)
{
    const int hz = blockIdx.z;
    A += (long)hz * aoz;
    W += (long)hz * woz;
    if (bias) bias += (long)hz * boz;
    C += (long)hz * coz;

    __shared__ float As[16][68];
    __shared__ float Ws[16][68];

    const int bm = blockIdx.y * 64;
    const int bn = blockIdx.x * 64;
    const int tid = threadIdx.x;
    const int tx = tid & 15;
    const int ty = tid >> 4;

    float acc[4][4] = {};

    for (int k0 = 0; k0 < K; k0 += 16) {
#pragma unroll
        for (int i = 0; i < 4; i++) {
            int idx = tid + i * 256;
            int r = idx >> 4, c = idx & 15;
            As[c][r] = A[(long)(bm + r) * lda + (k0 + c)];
            Ws[c][r] = W[(long)(bn + r) * ldw + (k0 + c)];
        }
        __syncthreads();
#pragma unroll
        for (int kk = 0; kk < 16; kk++) {
            const float4 a = *(const float4*)&As[kk][ty * 4];
            const float4 w = *(const float4*)&Ws[kk][tx * 4];
            acc[0][0] += a.x * w.x; acc[0][1] += a.x * w.y; acc[0][2] += a.x * w.z; acc[0][3] += a.x * w.w;
            acc[1][0] += a.y * w.x; acc[1][1] += a.y * w.y; acc[1][2] += a.y * w.z; acc[1][3] += a.y * w.w;
            acc[2][0] += a.z * w.x; acc[2][1] += a.z * w.y; acc[2][2] += a.z * w.z; acc[2][3] += a.z * w.w;
            acc[3][0] += a.w * w.x; acc[3][1] += a.w * w.y; acc[3][2] += a.w * w.z; acc[3][3] += a.w * w.w;
        }
        __syncthreads();
    }

    const int n0 = bn + tx * 4;
    float4 bv = make_float4(0.f, 0.f, 0.f, 0.f);
    if (bias) bv = *(const float4*)&bias[n0];
#pragma unroll
    for (int i = 0; i < 4; i++) {
        const int m = bm + ty * 4 + i;
        float4 r;
        if (rtab) {
            r.x = acc[i][0] * scale + rtab[rp[(n0 + 0) * 256 + m] * 8 + hz];
            r.y = acc[i][1] * scale + rtab[rp[(n0 + 1) * 256 + m] * 8 + hz];
            r.z = acc[i][2] * scale + rtab[rp[(n0 + 2) * 256 + m] * 8 + hz];
            r.w = acc[i][3] * scale + rtab[rp[(n0 + 3) * 256 + m] * 8 + hz];
        } else {
            r.x = (acc[i][0] + bv.x) * scale;
            r.y = (acc[i][1] + bv.y) * scale;
            r.z = (acc[i][2] + bv.z) * scale;
            r.w = (acc[i][3] + bv.w) * scale;
        }
        bf16 t4[4];
        t4[0] = __float2bfloat16(r.x);
        t4[1] = __float2bfloat16(r.y);
        t4[2] = __float2bfloat16(r.z);
        t4[3] = __float2bfloat16(r.w);
        *(uint2*)&C[(long)m * ldc + n0] = *(uint2*)t4;
    }
}

// ---------------------------------------------------------------------------
// Setup mega-kernel (role by blockIdx ranges)
// ---------------------------------------------------------------------------
constexpr int RB_A = 10368;
constexpr int RB_B = RB_A + 3456;
constexpr int RB_C = RB_B + 54;
constexpr int RB_D = RB_C + 6144;   // packed: 8192 rows x 192 f32x4 units
constexpr int RB_E = RB_D + 256;
constexpr int RB_F = RB_E + 1152;
constexpr int RB_G = RB_F + 2;

__global__ __launch_bounds__(256) void setup_mega_kernel(
    const int* __restrict__ tokens, const float* __restrict__ embed,
    const float* __restrict__ pos_emb,
    const float* __restrict__ pos_q_w, const float* __restrict__ pos_q_b,
    const float* __restrict__ pos_k_w, const float* __restrict__ pos_k_b,
    const float* __restrict__ pos_ln_g, const float* __restrict__ pos_ln_b,
    const float* __restrict__ Wq, const float* __restrict__ Wk,
    const float* __restrict__ Wv, const float* __restrict__ Wo,
    const float* __restrict__ bq, const float* __restrict__ bk,
    const float* __restrict__ bv,
    bf16* __restrict__ wqkv, bf16* __restrict__ woT, float* __restrict__ bqkv,
    bf16* __restrict__ xb, bf16* __restrict__ wln,
    bf16* __restrict__ wsW, float* __restrict__ wsB, float scale)
{
    const int bid = blockIdx.x, tid = threadIdx.x;

    if (bid < RB_A) {
        const long idx = (long)bid * 256 + tid;
        const long e = idx * 4;
        const int k = (int)(e % 768);
        const long nl = e / 768;
        const int n = (int)(nl % 2304);
        const int l = (int)(nl / 2304);
        const float* src;
        float sc = 1.f;
        if (n < 768)       { src = Wq + ((long)l * 768 + n) * 768; sc = scale; }
        else if (n < 1536) { src = Wk + ((long)l * 768 + (n - 768)) * 768; }
        else               { src = Wv + ((long)l * 768 + (n - 1536)) * 768; }
        const float4 v = *(const float4*)&src[k];
        bf16 tmp[4];
        tmp[0] = __float2bfloat16(v.x * sc);
        tmp[1] = __float2bfloat16(v.y * sc);
        tmp[2] = __float2bfloat16(v.z * sc);
        tmp[3] = __float2bfloat16(v.w * sc);
        *(uint2*)&wqkv[((long)l * 2304 + n) * 768 + k] = *(uint2*)tmp;
    } else if (bid < RB_B) {
        __shared__ float t[32][33];
        const int b2 = bid - RB_A;
        const int l = b2 / 576, r2 = b2 % 576;
        const int c0 = (r2 % 24) * 32, j0 = (r2 / 24) * 32;
        const int tx = tid & 31, ty = tid >> 5;
        const float* src = Wo + (long)l * 768 * 768;
#pragma unroll
        for (int rr = 0; rr < 32; rr += 8)
            t[ty + rr][tx] = src[(long)(c0 + ty + rr) * 768 + j0 + tx];
        __syncthreads();
        bf16* dst = woT + (long)l * 768 * 768;
#pragma unroll
        for (int rr = 0; rr < 32; rr += 8)
            dst[(long)(j0 + ty + rr) * 768 + c0 + tx] = __float2bfloat16(t[tx][ty + rr]);
    } else if (bid < RB_C) {
        const int idx = (bid - RB_B) * 256 + tid;
        if (idx < 6 * 2304) {
            const int n = idx % 2304, l = idx / 2304;
            float v;
            if (n < 768)       v = bq[l * 768 + n] * scale;
            else if (n < 1536) v = bk[l * 768 + (n - 768)];
            else               v = bv[l * 768 + (n - 1536)];
            bqkv[idx] = v;
        }
    } else if (bid < RB_D) {
        const int idx = (bid - RB_C) * 256 + tid;   // < 8192*192
        const int t = idx / 192;
        const int d = idx - t * 192;
        const int tok = tokens[t];
        const float4 v = ((const float4*)(embed + (long)tok * DIM))[d];
        bf16 tmp[4];
        tmp[0] = __float2bfloat16(v.x);
        tmp[1] = __float2bfloat16(v.y);
        tmp[2] = __float2bfloat16(v.z);
        tmp[3] = __float2bfloat16(v.w);
        *(uint2*)&xb[(long)t * DIM + d * 4] = *(uint2*)tmp;
    } else if (bid < RB_E) {
        __shared__ float buf[256];
        const int i = bid - RB_D;
        const float* row = pos_emb + (long)i * DIM;
        float v0 = row[tid], v1 = row[tid + 256], v2 = row[tid + 512];
        buf[tid] = v0 + v1 + v2;
        __syncthreads();
        for (int off = 128; off > 0; off >>= 1) {
            if (tid < off) buf[tid] += buf[tid + off];
            __syncthreads();
        }
        const float mean = buf[0] * (1.f / 768.f);
        __syncthreads();
        const float d0 = v0 - mean, d1 = v1 - mean, d2 = v2 - mean;
        buf[tid] = d0 * d0 + d1 * d1 + d2 * d2;
        __syncthreads();
        for (int off = 128; off > 0; off >>= 1) {
            if (tid < off) buf[tid] += buf[tid + off];
            __syncthreads();
        }
        const float rstd = rsqrtf(buf[0] * (1.f / 768.f) + 1e-5f);
        bf16* wr = wln + (long)i * DIM;
        wr[tid]       = __float2bfloat16(d0 * rstd * pos_ln_g[tid]       + pos_ln_b[tid]);
        wr[tid + 256] = __float2bfloat16(d1 * rstd * pos_ln_g[tid + 256] + pos_ln_b[tid + 256]);
        wr[tid + 512] = __float2bfloat16(d2 * rstd * pos_ln_g[tid + 512] + pos_ln_b[tid + 512]);
    } else if (bid < RB_F) {
        const long idx = (long)(bid - RB_E) * 256 + tid;
        const long e = idx * 4;
        const float4 v = (e < 589824) ? *(const float4*)&pos_q_w[e]
                                      : *(const float4*)&pos_k_w[e - 589824];
        bf16 tmp[4];
        tmp[0] = __float2bfloat16(v.x);
        tmp[1] = __float2bfloat16(v.y);
        tmp[2] = __float2bfloat16(v.z);
        tmp[3] = __float2bfloat16(v.w);
        *(uint2*)&wsW[e] = *(uint2*)tmp;
    } else {
        const int idx = (bid - RB_F) * 256 + tid;
        wsB[idx] = (idx < 768) ? pos_q_b[idx] : pos_k_b[idx - 768];
    }
}

// bf[l][n] = wqkv[l+1][n,:] . bo[l] + bqkv[l+1][n]   (l = 0..4)
__global__ __launch_bounds__(256) void fused_bias_kernel(
    const bf16* __restrict__ wqkv, const float* __restrict__ bo,
    const float* __restrict__ bqkv, float* __restrict__ bf_)
{
    const int l = blockIdx.y;
    const int lane = threadIdx.x & 63, wave = threadIdx.x >> 6;
    const int nloc = wave * 8 + (lane >> 3);
    const int seg = lane & 7;
    const int n = blockIdx.x * 32 + nloc;
    const bf16* wrow = wqkv + ((long)(l + 1) * 2304 + n) * 768 + seg * 96;
    const float* bsrc = bo + (long)l * 768 + seg * 96;
    float s = 0.f;
#pragma unroll
    for (int c8 = 0; c8 < 12; c8++) {
        const short8 w8 = *(const short8*)&wrow[c8 * 8];
#pragma unroll
        for (int e = 0; e < 8; e++) {
            bf16 b;
            *(short*)&b = w8[e];
            s += __bfloat162float(b) * bsrc[c8 * 8 + e];
        }
    }
    s += __shfl_xor(s, 1);
    s += __shfl_xor(s, 2);
    s += __shfl_xor(s, 4);
    if (seg == 0) bf_[l * 2304 + n] = s + bqkv[(l + 1) * 2304 + n];
}

// ---------------------------------------------------------------------------
// bf16 MFMA GEMM: 128x128 tile, BK=64, ping-pong double-buffered LDS.
// Cf != null: write f32 output. nofs: global column offset (remainder use).
// ---------------------------------------------------------------------------
#define GEMM_PREF(AS, BS, KB)                                                 \
  {                                                                           \
    _Pragma("unroll")                                                         \
    for (int i = 0; i < 2; i++) {                                             \
      const int u = tid + i * 512;                                            \
      const int r = u >> 3, c = u & 7;                                        \
      const int ca = c ^ (r & 7);                                             \
      ASYNC_COPY16(A + (bm + r) * (long)K + (KB) + ca * 8, &AS[u * 8]);       \
      ASYNC_COPY16(B + (bn + r) * (long)K + (KB) + ca * 8, &BS[u * 8]);       \
    }                                                                         \
  }

#define GEMM_COMPUTE(AS, BS)                                                  \
  {                                                                           \
    _Pragma("unroll")                                                         \
    for (int ks = 0; ks < 2; ks++) {                                          \
      const int cc = ks * 4 + quad;                                           \
      short8 af[4], bfr[2];                                                   \
      _Pragma("unroll")                                                       \
      for (int t = 0; t < 4; t++) {                                           \
        const int ra = wm * 64 + t * 16 + col;                                \
        af[t] = *(const short8*)&AS[ra * 64 + ((cc ^ (ra & 7)) * 8)];         \
      }                                                                       \
      _Pragma("unroll")                                                       \
      for (int t = 0; t < 2; t++) {                                           \
        const int rb = wn * 32 + t * 16 + col;                                \
        bfr[t] = *(const short8*)&BS[rb * 64 + ((cc ^ (rb & 7)) * 8)];        \
      }                                                                       \
      _Pragma("unroll")                                                       \
      for (int tm = 0; tm < 4; tm++)                                          \
        _Pragma("unroll")                                                     \
        for (int tn = 0; tn < 2; tn++)                                        \
          acc[tm][tn] = __builtin_amdgcn_mfma_f32_16x16x32_bf16(af[tm], bfr[tn], acc[tm][tn], 0, 0, 0); \
    }                                                                         \
  }

__global__ __launch_bounds__(512, 4) void gemm_bf16_kernel(
    const bf16* __restrict__ A, const bf16* __restrict__ B,
    const float* __restrict__ bias,
    bf16* __restrict__ Cb, bf16* __restrict__ vTout, float* __restrict__ Cf,
    int N, int K, int swz, long az, long bz, long cz, long biasz, int nofs, int skipQ)
{
    __shared__ bf16 As0[128 * 64];
    __shared__ bf16 Bs0[128 * 64];
    __shared__ bf16 As1[128 * 64];
    __shared__ bf16 Bs1[128 * 64];

    A += (long)blockIdx.z * az;
    B += (long)blockIdx.z * bz;
    if (Cb) Cb += (long)blockIdx.z * cz;
    if (Cf) Cf += (long)blockIdx.z * cz;
    if (bias) bias += (long)blockIdx.z * biasz;

    const int tid = threadIdx.x;
    const int lane = tid & 63, wave = tid >> 6;   // 8 waves
    const int wm = wave & 1, wn = wave >> 1;      // 2m x 4n

    int bmt, bnt;
    if (swz) {
        const int id = blockIdx.x + gridDim.x * blockIdx.y;
        const int xcd = id & 7, loc = id >> 3;
        bmt = xcd * 8 + (loc & 7);
        bnt = loc >> 3;
    } else {
        bmt = blockIdx.y;
        bnt = blockIdx.x;
    }
    if (skipQ && bnt < 6 && (bmt & 1)) return;

    const long bm = (long)bmt * 128, bn = (long)bnt * 128;
    const int col = lane & 15, quad = lane >> 4;

    f32x4 acc[4][2] = {};

    GEMM_PREF(As0, Bs0, 0);
    for (int kk = 0; kk < K; kk += 128) {
        __syncthreads();
        GEMM_PREF(As1, Bs1, kk + 64);
        GEMM_COMPUTE(As0, Bs0);
        __syncthreads();
        if (kk + 128 < K) GEMM_PREF(As0, Bs0, kk + 128);
        GEMM_COMPUTE(As1, Bs1);
    }

    const bool toVT = (vTout != nullptr) && (bn + nofs >= 1536);

    if (toVT) {
        // wave-local 64m x 32n transpose through LDS (4 KB scratch per wave)
        __syncthreads();
        bf16* tb = (wave < 4 ? As0 : Bs0) + (wave & 3) * 2048;
#pragma unroll
        for (int tn = 0; tn < 2; tn++) {
            const int nl = tn * 16 + col;                 // 0..31
            const float bvv = bias[nofs + bn + wn * 32 + nl];
#pragma unroll
            for (int tm = 0; tm < 4; tm++) {
                const int mc = tm * 4 + quad;             // 0..15 (4-bf16 m-chunk)
                bf16 t4[4];
#pragma unroll
                for (int r = 0; r < 4; r++)
                    t4[r] = __float2bfloat16(acc[tm][tn][r] + bvv);
                *(uint2*)&tb[(nl * 16 + (mc ^ (nl & 15))) * 4] = *(uint2*)t4;
            }
        }
        const int b_  = (int)((bm + wm * 64) >> 8);
        const int s0  = (int)((bm + wm * 64) & 255);
        const long nb = nofs + bn + wn * 32 - 1536;
#pragma unroll
        for (int it2 = 0; it2 < 8; it2++) {
            const int nl = it2 * 4 + quad;                // 0..31
            const uint2 v = *(const uint2*)&tb[(nl * 16 + (col ^ (nl & 15))) * 4];
            *(uint2*)&vTout[((long)b_ * 768 + nb + nl) * 256 + s0 + col * 4] = v;
        }
    } else if (Cf) {
#pragma unroll
        for (int tn = 0; tn < 2; tn++) {
            const long n = bn + wn * 32 + tn * 16 + col;
            const float bvv = bias ? bias[n] : 0.f;
#pragma unroll
            for (int tm = 0; tm < 4; tm++) {
                const long m0 = bm + wm * 64 + tm * 16 + quad * 4;
#pragma unroll
                for (int r = 0; r < 4; r++)
                    Cf[(m0 + r) * N + n] = acc[tm][tn][r] + bvv;
            }
        }
    } else {
#pragma unroll
        for (int tn = 0; tn < 2; tn++) {
            const long n = bn + wn * 32 + tn * 16 + col;
            const float bvv = bias ? bias[n] : 0.f;
#pragma unroll
            for (int tm = 0; tm < 4; tm++) {
                const long m0 = bm + wm * 64 + tm * 16 + quad * 4;
#pragma unroll
                for (int r = 0; r < 4; r++)
                    Cb[(m0 + r) * N + n] = __float2bfloat16(acc[tm][tn][r] + bvv);
            }
        }
    }
}

// ---------------------------------------------------------------------------
// R4: 8-phase 256x256 BK=64 MFMA GEMM (T3+T4 counted-vmcnt schedule) for the
// main layer GEMMs, n-tiles 0..7 (cols 0..2047). 512 thr / 8 waves (2m x 4n),
// wave tile 128x64, acc[8][4]. LDS 128KB: buf[2] x {A,B} x [Khalf][256][32],
// st_16x32 swizzle (XOR elem-16 by row&8) via pre-swizzled global source.
// Ledger: stage(kt,q0)=A@kt+1 Kh1, (q1)=B@kt+1 Kh1, (q2)=A@kt+2 Kh0,
// (q3)=B@kt+2 Kh0; vmcnt(4) at q3 (kt<10), vmcnt(0) at kt=10. One s_barrier
// per phase, placed [reads][stage][vmcnt?][barrier][16 MFMA].
// ---------------------------------------------------------------------------
#define STAGE256(matptr, dstTile, kt2, kh)                                    \
  { const bf16* gsrc = (matptr) + (long)stg_r * 768 + (kt2) * 64 + (kh) * 32 + stg_c * 8; \
    bf16* ldst = (dstTile) + (kh) * 8192 + stg_u * 8;                         \
    ASYNC_COPY16(gsrc, ldst);                                                 \
    ASYNC_COPY16(gsrc + 16 * 768, ldst + 512); }

#define LDA4(buf, ks, mh)                                                     \
  { _Pragma("unroll")                                                         \
    for (int t = 0; t < 4; t++) {                                             \
      const int row = wm * 128 + ((mh) * 4 + t) * 16 + col;                   \
      af[t] = *(const short8*)&(buf)[(ks) * 8192 + ((row * 32 + quad * 8) ^ ((row & 8) ? 16 : 0))]; } }

#define LDB4(buf, ks)                                                         \
  { _Pragma("unroll")                                                         \
    for (int t = 0; t < 4; t++) {                                             \
      const int row = wn * 64 + t * 16 + col;                                 \
      bfrag[t] = *(const short8*)&(buf)[(ks) * 8192 + ((row * 32 + quad * 8) ^ ((row & 8) ? 16 : 0))]; } }

#define MM16(mh)                                                              \
  { __builtin_amdgcn_s_setprio(1);                                            \
    _Pragma("unroll")                                                         \
    for (int tm = 0; tm < 4; tm++)                                            \
      _Pragma("unroll")                                                       \
      for (int tn = 0; tn < 4; tn++)                                          \
        acc[(mh) * 4 + tm][tn] = __builtin_amdgcn_mfma_f32_16x16x32_bf16(af[tm], bfrag[tn], acc[(mh) * 4 + tm][tn], 0, 0, 0); \
    __builtin_amdgcn_s_setprio(0); }

#define BAR() __builtin_amdgcn_s_barrier()

__global__ __launch_bounds__(512, 2) void gemm256_kernel(
    const bf16* __restrict__ A, const bf16* __restrict__ B,
    const float* __restrict__ bias, bf16* __restrict__ Cb,
    bf16* __restrict__ vTout, int N)
{
    __shared__ bf16 lds[2][2][16384];   // [buf][A|B][Khalf 8192 + Khalf 8192]

    const int tid = threadIdx.x;
    const int lane = tid & 63, wave = tid >> 6;   // 8 waves
    const int wm = wave & 1, wn = wave >> 1;      // 2m x 4n
    const int col = lane & 15, quad = lane >> 4;

    const int id = blockIdx.x;
    const int bnt = id & 7;          // one n-tile per XCD (B panel L2-resident)
    const int bmt = id >> 3;         // 0..31
    const long bm = (long)bmt * 256;

    const bf16* Ab = A + bm * 768;
    const bf16* Bb = B + (long)bnt * 256 * 768;

    // staging address components (per thread)
    const int stg_u = wave * 128 + lane;                 // *8 elems = dest
    const int stg_r = wave * 32 + (lane >> 2);           // source row (j=0)
    const int stg_c = (lane & 3) ^ ((lane >> 4) & 2);    // swizzled 8-col chunk

    bf16* ldsA0 = &lds[0][0][0];
    bf16* ldsB0 = &lds[0][1][0];
    bf16* ldsA1 = &lds[1][0][0];
    bf16* ldsB1 = &lds[1][1][0];

    f32x4 acc[8][4] = {};
    short8 af[4], bfrag[4];

    // prologue: kt0 fully + kt1 Kh0 pair  (6 halves, 12 loads/wave)
    STAGE256(Ab, ldsA0, 0, 0);
    STAGE256(Bb, ldsB0, 0, 0);
    STAGE256(Ab, ldsA0, 0, 1);
    STAGE256(Bb, ldsB0, 0, 1);
    STAGE256(Ab, ldsA1, 1, 0);
    STAGE256(Bb, ldsB1, 1, 0);
    asm volatile("s_waitcnt vmcnt(4)" ::: "memory");   // kt0 landed
    BAR();

#pragma unroll 2
    for (int kt = 0; kt < 12; kt++) {
        bf16* Abuf  = (kt & 1) ? ldsA1 : ldsA0;
        bf16* Bbuf  = (kt & 1) ? ldsB1 : ldsB0;
        bf16* AbufN = (kt & 1) ? ldsA0 : ldsA1;
        bf16* BbufN = (kt & 1) ? ldsB0 : ldsB1;

        // q0: ks0 mh0
        LDA4(Abuf, 0, 0);
        LDB4(Bbuf, 0);
        if (kt <= 10) STAGE256(Ab, AbufN, kt + 1, 1);
        BAR();
        MM16(0);

        // q1: ks0 mh1
        LDA4(Abuf, 0, 1);
        if (kt <= 10) STAGE256(Bb, BbufN, kt + 1, 1);
        BAR();
        MM16(1);

        // q2: ks1 mh0
        LDA4(Abuf, 1, 0);
        LDB4(Bbuf, 1);
        if (kt <= 9) STAGE256(Ab, Abuf, kt + 2, 0);
        BAR();
        MM16(0);

        // q3: ks1 mh1
        LDA4(Abuf, 1, 1);
        if (kt <= 9) STAGE256(Bb, Bbuf, kt + 2, 0);
        if (kt < 10) {
            asm volatile("s_waitcnt vmcnt(4)" ::: "memory");  // kt+1 landed
        } else if (kt == 10) {
            asm volatile("s_waitcnt vmcnt(0)" ::: "memory");  // drain for kt11
        }
        BAR();
        MM16(1);
    }

    if (bnt >= 6) {
        // V columns -> vT[b][n-1536][s], via per-wave LDS transpose chunks
        __syncthreads();
        bf16* tb = &lds[0][0][0] + wave * 2048;     // 4KB scratch per wave
        const long nbase = (long)bnt * 256 + wn * 64;
#pragma unroll
        for (int cm2 = 0; cm2 < 2; cm2++) {
#pragma unroll
            for (int cn2 = 0; cn2 < 2; cn2++) {
#pragma unroll
                for (int tn = 0; tn < 2; tn++) {
                    const int nl = tn * 16 + col;             // 0..31
                    const float bvv = bias[nbase + cn2 * 32 + nl];
#pragma unroll
                    for (int tm = 0; tm < 4; tm++) {
                        const int mc = tm * 4 + quad;         // 0..15
                        const f32x4 a = acc[cm2 * 4 + tm][cn2 * 2 + tn];
                        bf16 t4[4];
#pragma unroll
                        for (int r = 0; r < 4; r++)
                            t4[r] = __float2bfloat16(a[r] + bvv);
                        *(uint2*)&tb[(nl * 16 + (mc ^ (nl & 15))) * 4] = *(uint2*)t4;
                    }
                }
                const int s0 = wm * 128 + cm2 * 64;
                const long nb = nbase + cn2 * 32 - 1536;
#pragma unroll
                for (int it2 = 0; it2 < 8; it2++) {
                    const int nl = it2 * 4 + quad;            // 0..31
                    const uint2 v = *(const uint2*)&tb[(nl * 16 + (col ^ (nl & 15))) * 4];
                    *(uint2*)&vTout[((long)bmt * 768 + nb + nl) * 256 + s0 + col * 4] = v;
                }
            }
        }
    } else {
#pragma unroll
        for (int nf = 0; nf < 4; nf++) {
            const long n = (long)bnt * 256 + wn * 64 + nf * 16 + col;
            const float bvv = bias[n];
#pragma unroll
            for (int mf = 0; mf < 8; mf++) {
                const long m0 = bm + wm * 128 + mf * 16 + quad * 4;
#pragma unroll
                for (int r = 0; r < 4; r++)
                    Cb[(m0 + r) * N + n] = __float2bfloat16(acc[mf][nf][r] + bvv);
            }
        }
    }
}

// ---------------------------------------------------------------------------
// MFMA attention (R3 state: Ps-halved, 3 blocks/CU, XCD head affinity).
// ---------------------------------------------------------------------------
#define PREF_K(DST, JC)                                                      \
  { _Pragma("unroll")                                                        \
    for (int i = 0; i < 4; i++) {                                            \
      const int u = tid + i * 256;                                           \
      const int r = u >> 4, pp = u & 15;                                     \
      const int c = pp ^ (r & 15);                                           \
      ASYNC_COPY16(kbase + ((JC) * 64 + r) * 2304 + c * 8, &DST[u * 8]);     \
    } }

#define PREF_V(DST, KC)                                                      \
  { _Pragma("unroll")                                                        \
    for (int i = 0; i < 3; i++) {                                            \
      const int u = tid + i * 256;                                           \
      const int r = u >> 3, pp = u & 7;                                      \
      const int c = pp ^ (r & 7);                                            \
      ASYNC_COPY16(vbase + r * 256 + (KC) * 64 + c * 8, &DST[u * 8]);        \
    } }

#define SCORE(BUF, JC)                                                       \
  { __builtin_amdgcn_s_setprio(1);                                           \
    _Pragma("unroll")                                                        \
    for (int ks = 0; ks < 3; ks++) {                                         \
      _Pragma("unroll")                                                      \
      for (int jt2 = 0; jt2 < 4; jt2++) {                                    \
        const int row = jt2 * 16 + col;                                      \
        const int c = ks * 4 + quad;                                         \
        const short8 bk_ = *(const short8*)&BUF[row * 128 + ((c ^ (row & 15)) * 8)]; \
        accS[(JC) * 4 + jt2] = __builtin_amdgcn_mfma_f32_16x16x32_bf16(aq[ks], bk_, accS[(JC) * 4 + jt2], 0, 0, 0); \
      } }                                                                     \
    __builtin_amdgcn_s_setprio(0); }

// PC = P-column block (0 or 1) within the current Ps half
#define PV(BUF, PC)                                                          \
  { __builtin_amdgcn_s_setprio(1);                                           \
    _Pragma("unroll")                                                        \
    for (int k2 = 0; k2 < 2; k2++) {                                         \
      const short8 ap = *(const short8*)&Ps[(wave * 16 + col) * PS + (PC) * 64 + k2 * 32 + quad * 8]; \
      _Pragma("unroll")                                                      \
      for (int nt = 0; nt < 6; nt++) {                                       \
        const int row = nt * 16 + col;                                       \
        const int c = k2 * 4 + quad;                                         \
        const short8 bv_ = *(const short8*)&BUF[row * 64 + ((c ^ (row & 7)) * 8)]; \
        accO[nt] = __builtin_amdgcn_mfma_f32_16x16x32_bf16(ap, bv_, accO[nt], 0, 0, 0); \
      } }                                                                     \
    __builtin_amdgcn_s_setprio(0); }

__global__ __launch_bounds__(256, 3) void attn_mfma_kernel(
    const bf16* __restrict__ qkv, const bf16* __restrict__ vT,
    const bf16* __restrict__ biasT, bf16* __restrict__ o)
{
    constexpr int PS = 136;
    __shared__ bf16 Ps[64 * PS];      // 17.0 KB (half of P at a time)
    __shared__ bf16 KV0[64 * 128];    // 16 KB
    __shared__ bf16 KV1[64 * 128];    // 16 KB

    const int blk = blockIdx.x;
    const int h  = blk & 7;           // XCD-affine: one head per XCD
    const int b  = (blk >> 3) & 31;
    const int it = blk >> 8;
    const int i0 = it * 64;
    const int tid = threadIdx.x, lane = tid & 63, wave = tid >> 6;
    const int col = lane & 15, quad = lane >> 4;
    const long rowbase = (long)b * SEQ;

    const bf16* kbase = qkv + rowbase * 2304 + 768 + h * 96;
    const bf16* vbase = vT + ((long)b * 768 + h * 96) * 256;

    PREF_K(KV0, 0);

    short8 aq[3];
    {
        const bf16* qrow = qkv + (rowbase + i0 + wave * 16 + col) * 2304 + h * 96;
#pragma unroll
        for (int ks = 0; ks < 3; ks++)
            aq[ks] = *(const short8*)&qrow[ks * 32 + quad * 8];
    }

    f32x4 accS[16] = {};
    __syncthreads();
    PREF_K(KV1, 1);
    SCORE(KV0, 0);
    __syncthreads();
    PREF_K(KV0, 2);
    SCORE(KV1, 1);
    __syncthreads();
    PREF_K(KV1, 3);
    SCORE(KV0, 2);
    __syncthreads();
    PREF_V(KV0, 0);
    SCORE(KV1, 3);

    const bf16* bbT = biasT + (long)h * SEQ * SEQ + i0 + wave * 16 + quad * 4;
#pragma unroll
    for (int jt = 0; jt < 16; jt++) {
        bf16 b4[4];
        *(uint2*)b4 = *(const uint2*)&bbT[(long)(jt * 16 + col) * SEQ];
        accS[jt][0] += __bfloat162float(b4[0]);
        accS[jt][1] += __bfloat162float(b4[1]);
        accS[jt][2] += __bfloat162float(b4[2]);
        accS[jt][3] += __bfloat162float(b4[3]);
    }

#pragma unroll
    for (int r = 0; r < 4; r++) {
        float t0 = fmaxf(fmaxf(accS[0][r],  accS[1][r]),  accS[2][r]);
        float t1 = fmaxf(fmaxf(accS[3][r],  accS[4][r]),  accS[5][r]);
        float t2 = fmaxf(fmaxf(accS[6][r],  accS[7][r]),  accS[8][r]);
        float t3 = fmaxf(fmaxf(accS[9][r],  accS[10][r]), accS[11][r]);
        float t4 = fmaxf(fmaxf(accS[12][r], accS[13][r]), accS[14][r]);
        float m  = fmaxf(fmaxf(fmaxf(t0, t1), t2), fmaxf(fmaxf(t3, t4), accS[15][r]));
        for (int d = 1; d < 16; d <<= 1) m = fmaxf(m, __shfl_xor(m, d));
        float s = 0.f;
#pragma unroll
        for (int jt = 0; jt < 16; jt++) {
            const float e = __expf(accS[jt][r] - m);
            accS[jt][r] = e;
            s += e;
        }
        for (int d = 1; d < 16; d <<= 1) s += __shfl_xor(s, d);
        const float inv = __builtin_amdgcn_rcpf(s);
#pragma unroll
        for (int jt = 0; jt < 16; jt++) accS[jt][r] *= inv;
        const int prow = wave * 16 + quad * 4 + r;
#pragma unroll
        for (int jt = 0; jt < 8; jt++)
            Ps[prow * PS + jt * 16 + col] = __float2bfloat16(accS[jt][r]);
    }
    // no barrier for Ps: each wave reads only the rows it wrote

    f32x4 accO[6] = {};
    __syncthreads();
    PREF_V(KV1, 1);
    PV(KV0, 0);
    __syncthreads();
    PREF_V(KV0, 2);
    PV(KV1, 1);
    // overwrite wave-private Ps rows with keys 128..255 (program order per
    // wave guarantees prior PV reads of this region are complete)
#pragma unroll
    for (int r = 0; r < 4; r++) {
        const int prow = wave * 16 + quad * 4 + r;
#pragma unroll
        for (int jt = 8; jt < 16; jt++)
            Ps[prow * PS + (jt - 8) * 16 + col] = __float2bfloat16(accS[jt][r]);
    }
    __syncthreads();
    PREF_V(KV1, 3);
    PV(KV0, 0);                        // keys 128..191
    __syncthreads();
    PV(KV1, 1);                        // keys 192..255

#pragma unroll
    for (int nt = 0; nt < 6; nt++)
#pragma unroll
        for (int r = 0; r < 4; r++) {
            const long m = rowbase + i0 + wave * 16 + quad * 4 + r;
            o[m * DIM + h * 96 + nt * 16 + col] = __float2bfloat16(accO[nt][r]);
        }
}

// out[b, ng*32 + tid>>3] = ob[b*256,:] . Wo5[n,:] + bo5[n]
__global__ __launch_bounds__(256) void final_out_kernel(
    const bf16* __restrict__ ob, const float* __restrict__ Wo5,
    const float* __restrict__ bo5, float* __restrict__ out)
{
    __shared__ float os[768];
    const int b = blockIdx.y, ng = blockIdx.x, tid = threadIdx.x;
    const bf16* orow = ob + (long)b * 256 * 768;
    for (int i = tid; i < 768; i += 256) os[i] = __bfloat162float(orow[i]);
    __syncthreads();

    const int n = ng * 32 + (tid >> 3);
    const int seg = tid & 7;
    const float* wrow = Wo5 + (long)n * 768 + seg * 96;
    const float* xs = &os[seg * 96];
    float s = 0.f;
#pragma unroll
    for (int k = 0; k < 96; k += 4) {
        const float4 w = *(const float4*)&wrow[k];
        s += xs[k] * w.x + xs[k + 1] * w.y + xs[k + 2] * w.z + xs[k + 3] * w.w;
    }
    s += __shfl_xor(s, 1);
    s += __shfl_xor(s, 2);
    s += __shfl_xor(s, 4);
    if (seg == 0) out[b * 768 + n] = s + bo5[n];
}

extern "C" void kernel_launch(void* const* d_in, const int* in_sizes, int n_in,
                              void* d_out, int out_size, void* d_ws, size_t ws_size,
                              hipStream_t stream)
{
    const int*   tokens   = (const int*)d_in[0];
    const float* embed    = (const float*)d_in[1];
    const float* pos_emb  = (const float*)d_in[2];
    const float* pos_q_w  = (const float*)d_in[3];
    const float* pos_q_b  = (const float*)d_in[4];
    const float* pos_k_w  = (const float*)d_in[5];
    const float* pos_k_b  = (const float*)d_in[6];
    const float* pos_ln_g = (const float*)d_in[7];
    const float* pos_ln_b = (const float*)d_in[8];
    const float* rel_tab  = (const float*)d_in[9];
    const int*   rp       = (const int*)d_in[10];
    const float* Wq = (const float*)d_in[11];
    const float* bq = (const float*)d_in[12];
    const float* Wk = (const float*)d_in[13];
    const float* bk = (const float*)d_in[14];
    const float* Wv = (const float*)d_in[15];
    const float* bv = (const float*)d_in[16];
    const float* Wo = (const float*)d_in[17];
    const float* bo = (const float*)d_in[18];
    float* out = (float*)d_out;

    char* p = (char*)d_ws;
    auto alloc = [&](size_t bytes) -> char* {
        char* r = p;
        p += (bytes + 255) & ~(size_t)255;
        return r;
    };
    const long NT = 32L * SEQ;  // 8192

    bf16*  biasT = (bf16*) alloc(8L * SEQ * SEQ * 2);       // [h][j][i] bf16
    bf16*  wlnb  = (bf16*) alloc((long)SEQ * DIM * 2);
    float* pqk   = (float*)alloc(2L * SEQ * DIM * 4);       // pq | pk (f32)
    bf16*  wsWb  = (bf16*) alloc(2L * 768 * 768 * 2);       // posq_w | posk_w bf16
    float* wsB   = (float*)alloc(2L * 768 * 4);
    bf16*  xb    = (bf16*) alloc(NT * DIM * 2);
    bf16*  qkv   = (bf16*) alloc(NT * 2304 * 2);
    bf16*  vT    = (bf16*) alloc(NT * DIM * 2);             // [32][768][256]
    bf16*  ob    = (bf16*) alloc(NT * DIM * 2);
    bf16*  wqkv  = (bf16*) alloc(6L * 2304 * 768 * 2);
    bf16*  woT   = (bf16*) alloc(6L * 768 * 768 * 2);
    bf16*  wf    = (bf16*) alloc(5L * 2304 * 768 * 2);
    float* bqkv  = (float*)alloc(6L * 2304 * 4);
    float* bfus  = (float*)alloc(5L * 2304 * 4);

    const float SCALE = 0.07216878364870322f;   // (HD*2)^-0.5

    // ---- all independent setup in ONE launch ----
    setup_mega_kernel<<<RB_G, 256, 0, stream>>>(
        tokens, embed, pos_emb, pos_q_w, pos_q_b, pos_k_w, pos_k_b,
        pos_ln_g, pos_ln_b, Wq, Wk, Wv, Wo, bq, bk, bv,
        wqkv, woT, bqkv, xb, wlnb, wsWb, wsB, SCALE);

    // Wf_l = Wqkv_{l+1} . Wo_l  (batched, z = l)
    gemm_bf16_kernel<<<dim3(6, 18, 5), 512, 0, stream>>>(
        wqkv + 2304L * 768, woT, nullptr, wf, nullptr, nullptr, 768, 768, 0,
        2304L * 768, 768L * 768, 2304L * 768, 0, 0, 0);
    fused_bias_kernel<<<dim3(72, 5), 256, 0, stream>>>(wqkv, bo, bqkv, bfus);

    // pos projections pq|pk via MFMA (bf16 in, f32 out), z = {q, k}
    gemm_bf16_kernel<<<dim3(6, 2, 2), 512, 0, stream>>>(
        wlnb, wsWb, wsB, nullptr, nullptr, pqk, 768, 768, 0,
        0, 768L * 768, (long)SEQ * DIM, 768, 0, 0);
    // biasT[h][j][i] = SCALE * (pk_j . pq_i) + rel[i,j,h]   (bf16 out)
    gemm_kernel<<<dim3(4, 4, NH), 256, 0, stream>>>(
        pqk + (long)SEQ * DIM, DIM, HD, pqk, DIM, HD, nullptr, 0,
        biasT, SEQ, (long)SEQ * SEQ, SEQ, SEQ, HD, SCALE, rp, rel_tab);

    // ---- layer pipeline: 8-phase 256² kernel (cols 0..2047, 256 blocks =
    // 1/CU exact) + existing 128² kernel for the V-remainder cols 2048..2303 ----
    gemm256_kernel<<<256, 512, 0, stream>>>(xb, wqkv, bqkv, qkv, vT, 2304);
    gemm_bf16_kernel<<<dim3(2, 64, 1), 512, 0, stream>>>(
        xb, wqkv + 2048L * 768, bqkv, nullptr, vT, nullptr,
        2304, 768, 0, 0, 0, 0, 0, 2048, 0);
    for (int l = 0; l < 5; l++) {
        attn_mfma_kernel<<<1024, 256, 0, stream>>>(qkv, vT, biasT, ob);
        gemm256_kernel<<<256, 512, 0, stream>>>(
            ob, wf + (long)l * 2304 * 768, bfus + (long)l * 2304, qkv, vT, 2304);
        gemm_bf16_kernel<<<dim3(2, 64, 1), 512, 0, stream>>>(
            ob, wf + (long)l * 2304 * 768 + 2048L * 768, bfus + (long)l * 2304,
            nullptr, vT, nullptr, 2304, 768, 0, 0, 0, 0, 0, 2048, 0);
    }
    attn_mfma_kernel<<<256, 256, 0, stream>>>(qkv, vT, biasT, ob);   // it=0 only
    final_out_kernel<<<dim3(24, 32), 256, 0, stream>>>(ob, Wo + 5L * 768 * 768, bo + 5L * 768, out);
}

// Round 5
// 651.712 us; speedup vs baseline: 1.0557x; 1.0557x over previous
//
#include <hip/hip_runtime.h>
#include <hip/hip_bf16.h>
#include <math.h>

constexpr int SEQ = 256;
constexpr int DIM = 768;
constexpr int NH  = 8;
constexpr int HD  = 96;

typedef __attribute__((ext_vector_type(8))) short short8;
typedef __attribute__((ext_vector_type(4))) float f32x4;
using bf16 = __hip_bfloat16;

#define ASYNC_COPY16(gptr, lptr) \
  __builtin_amdgcn_global_load_lds((const __attribute__((address_space(1))) void*)(gptr), \
                                   (__attribute__((address_space(3))) void*)(lptr), 16, 0, 0)

// ---------------------------------------------------------------------------
// f32 tiled GEMM (biasT only now): C[m,n] = acc*scale + rtab[rp[n*256+m]*8+hz]
// C written as bf16.
// ---------------------------------------------------------------------------
__global__ __launch_bounds__(256) void gemm_kernel(
    const float* __restrict__ A, int lda, long aoz,
    const float* __restrict__ W, int ldw, long woz,
    const float* __restrict__ bias, long boz,
    bf16* __restrict__ C, int ldc, long coz,
    int M, int N, int K, float scale,
    const int* __restrict__ rp, const float* __restrict__ rtab)
{
    const int hz = blockIdx.z;
    A += (long)hz * aoz;
    W += (long)hz * woz;
    if (bias) bias += (long)hz * boz;
    C += (long)hz * coz;

    __shared__ float As[16][68];
    __shared__ float Ws[16][68];

    const int bm = blockIdx.y * 64;
    const int bn = blockIdx.x * 64;
    const int tid = threadIdx.x;
    const int tx = tid & 15;
    const int ty = tid >> 4;

    float acc[4][4] = {};

    for (int k0 = 0; k0 < K; k0 += 16) {
#pragma unroll
        for (int i = 0; i < 4; i++) {
            int idx = tid + i * 256;
            int r = idx >> 4, c = idx & 15;
            As[c][r] = A[(long)(bm + r) * lda + (k0 + c)];
            Ws[c][r] = W[(long)(bn + r) * ldw + (k0 + c)];
        }
        __syncthreads();
#pragma unroll
        for (int kk = 0; kk < 16; kk++) {
            const float4 a = *(const float4*)&As[kk][ty * 4];
            const float4 w = *(const float4*)&Ws[kk][tx * 4];
            acc[0][0] += a.x * w.x; acc[0][1] += a.x * w.y; acc[0][2] += a.x * w.z; acc[0][3] += a.x * w.w;
            acc[1][0] += a.y * w.x; acc[1][1] += a.y * w.y; acc[1][2] += a.y * w.z; acc[1][3] += a.y * w.w;
            acc[2][0] += a.z * w.x; acc[2][1] += a.z * w.y; acc[2][2] += a.z * w.z; acc[2][3] += a.z * w.w;
            acc[3][0] += a.w * w.x; acc[3][1] += a.w * w.y; acc[3][2] += a.w * w.z; acc[3][3] += a.w * w.w;
        }
        __syncthreads();
    }

    const int n0 = bn + tx * 4;
    float4 bv = make_float4(0.f, 0.f, 0.f, 0.f);
    if (bias) bv = *(const float4*)&bias[n0];
#pragma unroll
    for (int i = 0; i < 4; i++) {
        const int m = bm + ty * 4 + i;
        float4 r;
        if (rtab) {
            r.x = acc[i][0] * scale + rtab[rp[(n0 + 0) * 256 + m] * 8 + hz];
            r.y = acc[i][1] * scale + rtab[rp[(n0 + 1) * 256 + m] * 8 + hz];
            r.z = acc[i][2] * scale + rtab[rp[(n0 + 2) * 256 + m] * 8 + hz];
            r.w = acc[i][3] * scale + rtab[rp[(n0 + 3) * 256 + m] * 8 + hz];
        } else {
            r.x = (acc[i][0] + bv.x) * scale;
            r.y = (acc[i][1] + bv.y) * scale;
            r.z = (acc[i][2] + bv.z) * scale;
            r.w = (acc[i][3] + bv.w) * scale;
        }
        bf16 t4[4];
        t4[0] = __float2bfloat16(r.x);
        t4[1] = __float2bfloat16(r.y);
        t4[2] = __float2bfloat16(r.z);
        t4[3] = __float2bfloat16(r.w);
        *(uint2*)&C[(long)m * ldc + n0] = *(uint2*)t4;
    }
}

// ---------------------------------------------------------------------------
// Setup mega-kernel (role by blockIdx ranges)
// ---------------------------------------------------------------------------
constexpr int RB_A = 10368;
constexpr int RB_B = RB_A + 3456;
constexpr int RB_C = RB_B + 54;
constexpr int RB_D = RB_C + 6144;   // packed: 8192 rows x 192 f32x4 units
constexpr int RB_E = RB_D + 256;
constexpr int RB_F = RB_E + 1152;
constexpr int RB_G = RB_F + 2;

__global__ __launch_bounds__(256) void setup_mega_kernel(
    const int* __restrict__ tokens, const float* __restrict__ embed,
    const float* __restrict__ pos_emb,
    const float* __restrict__ pos_q_w, const float* __restrict__ pos_q_b,
    const float* __restrict__ pos_k_w, const float* __restrict__ pos_k_b,
    const float* __restrict__ pos_ln_g, const float* __restrict__ pos_ln_b,
    const float* __restrict__ Wq, const float* __restrict__ Wk,
    const float* __restrict__ Wv, const float* __restrict__ Wo,
    const float* __restrict__ bq, const float* __restrict__ bk,
    const float* __restrict__ bv,
    bf16* __restrict__ wqkv, bf16* __restrict__ woT, float* __restrict__ bqkv,
    bf16* __restrict__ xb, bf16* __restrict__ wln,
    bf16* __restrict__ wsW, float* __restrict__ wsB, float scale)
{
    const int bid = blockIdx.x, tid = threadIdx.x;

    if (bid < RB_A) {
        const long idx = (long)bid * 256 + tid;
        const long e = idx * 4;
        const int k = (int)(e % 768);
        const long nl = e / 768;
        const int n = (int)(nl % 2304);
        const int l = (int)(nl / 2304);
        const float* src;
        float sc = 1.f;
        if (n < 768)       { src = Wq + ((long)l * 768 + n) * 768; sc = scale; }
        else if (n < 1536) { src = Wk + ((long)l * 768 + (n - 768)) * 768; }
        else               { src = Wv + ((long)l * 768 + (n - 1536)) * 768; }
        const float4 v = *(const float4*)&src[k];
        bf16 tmp[4];
        tmp[0] = __float2bfloat16(v.x * sc);
        tmp[1] = __float2bfloat16(v.y * sc);
        tmp[2] = __float2bfloat16(v.z * sc);
        tmp[3] = __float2bfloat16(v.w * sc);
        *(uint2*)&wqkv[((long)l * 2304 + n) * 768 + k] = *(uint2*)tmp;
    } else if (bid < RB_B) {
        __shared__ float t[32][33];
        const int b2 = bid - RB_A;
        const int l = b2 / 576, r2 = b2 % 576;
        const int c0 = (r2 % 24) * 32, j0 = (r2 / 24) * 32;
        const int tx = tid & 31, ty = tid >> 5;
        const float* src = Wo + (long)l * 768 * 768;
#pragma unroll
        for (int rr = 0; rr < 32; rr += 8)
            t[ty + rr][tx] = src[(long)(c0 + ty + rr) * 768 + j0 + tx];
        __syncthreads();
        bf16* dst = woT + (long)l * 768 * 768;
#pragma unroll
        for (int rr = 0; rr < 32; rr += 8)
            dst[(long)(j0 + ty + rr) * 768 + c0 + tx] = __float2bfloat16(t[tx][ty + rr]);
    } else if (bid < RB_C) {
        const int idx = (bid - RB_B) * 256 + tid;
        if (idx < 6 * 2304) {
            const int n = idx % 2304, l = idx / 2304;
            float v;
            if (n < 768)       v = bq[l * 768 + n] * scale;
            else if (n < 1536) v = bk[l * 768 + (n - 768)];
            else               v = bv[l * 768 + (n - 1536)];
            bqkv[idx] = v;
        }
    } else if (bid < RB_D) {
        const int idx = (bid - RB_C) * 256 + tid;   // < 8192*192
        const int t = idx / 192;
        const int d = idx - t * 192;
        const int tok = tokens[t];
        const float4 v = ((const float4*)(embed + (long)tok * DIM))[d];
        bf16 tmp[4];
        tmp[0] = __float2bfloat16(v.x);
        tmp[1] = __float2bfloat16(v.y);
        tmp[2] = __float2bfloat16(v.z);
        tmp[3] = __float2bfloat16(v.w);
        *(uint2*)&xb[(long)t * DIM + d * 4] = *(uint2*)tmp;
    } else if (bid < RB_E) {
        __shared__ float buf[256];
        const int i = bid - RB_D;
        const float* row = pos_emb + (long)i * DIM;
        float v0 = row[tid], v1 = row[tid + 256], v2 = row[tid + 512];
        buf[tid] = v0 + v1 + v2;
        __syncthreads();
        for (int off = 128; off > 0; off >>= 1) {
            if (tid < off) buf[tid] += buf[tid + off];
            __syncthreads();
        }
        const float mean = buf[0] * (1.f / 768.f);
        __syncthreads();
        const float d0 = v0 - mean, d1 = v1 - mean, d2 = v2 - mean;
        buf[tid] = d0 * d0 + d1 * d1 + d2 * d2;
        __syncthreads();
        for (int off = 128; off > 0; off >>= 1) {
            if (tid < off) buf[tid] += buf[tid + off];
            __syncthreads();
        }
        const float rstd = rsqrtf(buf[0] * (1.f / 768.f) + 1e-5f);
        bf16* wr = wln + (long)i * DIM;
        wr[tid]       = __float2bfloat16(d0 * rstd * pos_ln_g[tid]       + pos_ln_b[tid]);
        wr[tid + 256] = __float2bfloat16(d1 * rstd * pos_ln_g[tid + 256] + pos_ln_b[tid + 256]);
        wr[tid + 512] = __float2bfloat16(d2 * rstd * pos_ln_g[tid + 512] + pos_ln_b[tid + 512]);
    } else if (bid < RB_F) {
        const long idx = (long)(bid - RB_E) * 256 + tid;
        const long e = idx * 4;
        const float4 v = (e < 589824) ? *(const float4*)&pos_q_w[e]
                                      : *(const float4*)&pos_k_w[e - 589824];
        bf16 tmp[4];
        tmp[0] = __float2bfloat16(v.x);
        tmp[1] = __float2bfloat16(v.y);
        tmp[2] = __float2bfloat16(v.z);
        tmp[3] = __float2bfloat16(v.w);
        *(uint2*)&wsW[e] = *(uint2*)tmp;
    } else {
        const int idx = (bid - RB_F) * 256 + tid;
        wsB[idx] = (idx < 768) ? pos_q_b[idx] : pos_k_b[idx - 768];
    }
}

// bf[l][n] = wqkv[l+1][n,:] . bo[l] + bqkv[l+1][n]   (l = 0..4)
__global__ __launch_bounds__(256) void fused_bias_kernel(
    const bf16* __restrict__ wqkv, const float* __restrict__ bo,
    const float* __restrict__ bqkv, float* __restrict__ bf_)
{
    const int l = blockIdx.y;
    const int lane = threadIdx.x & 63, wave = threadIdx.x >> 6;
    const int nloc = wave * 8 + (lane >> 3);
    const int seg = lane & 7;
    const int n = blockIdx.x * 32 + nloc;
    const bf16* wrow = wqkv + ((long)(l + 1) * 2304 + n) * 768 + seg * 96;
    const float* bsrc = bo + (long)l * 768 + seg * 96;
    float s = 0.f;
#pragma unroll
    for (int c8 = 0; c8 < 12; c8++) {
        const short8 w8 = *(const short8*)&wrow[c8 * 8];
#pragma unroll
        for (int e = 0; e < 8; e++) {
            bf16 b;
            *(short*)&b = w8[e];
            s += __bfloat162float(b) * bsrc[c8 * 8 + e];
        }
    }
    s += __shfl_xor(s, 1);
    s += __shfl_xor(s, 2);
    s += __shfl_xor(s, 4);
    if (seg == 0) bf_[l * 2304 + n] = s + bqkv[(l + 1) * 2304 + n];
}

// ---------------------------------------------------------------------------
// bf16 MFMA GEMM: 128x128 tile, BK=64, ping-pong double-buffered LDS.
// Cf != null: write f32 output (used for pos projections pq|pk).
// ---------------------------------------------------------------------------
#define GEMM_PREF(AS, BS, KB)                                                 \
  {                                                                           \
    _Pragma("unroll")                                                         \
    for (int i = 0; i < 2; i++) {                                             \
      const int u = tid + i * 512;                                            \
      const int r = u >> 3, c = u & 7;                                        \
      const int ca = c ^ (r & 7);                                             \
      ASYNC_COPY16(A + (bm + r) * (long)K + (KB) + ca * 8, &AS[u * 8]);       \
      ASYNC_COPY16(B + (bn + r) * (long)K + (KB) + ca * 8, &BS[u * 8]);       \
    }                                                                         \
  }

#define GEMM_COMPUTE(AS, BS)                                                  \
  {                                                                           \
    _Pragma("unroll")                                                         \
    for (int ks = 0; ks < 2; ks++) {                                          \
      const int cc = ks * 4 + quad;                                           \
      short8 af[4], bfr[2];                                                   \
      _Pragma("unroll")                                                       \
      for (int t = 0; t < 4; t++) {                                           \
        const int ra = wm * 64 + t * 16 + col;                                \
        af[t] = *(const short8*)&AS[ra * 64 + ((cc ^ (ra & 7)) * 8)];         \
      }                                                                       \
      _Pragma("unroll")                                                       \
      for (int t = 0; t < 2; t++) {                                           \
        const int rb = wn * 32 + t * 16 + col;                                \
        bfr[t] = *(const short8*)&BS[rb * 64 + ((cc ^ (rb & 7)) * 8)];        \
      }                                                                       \
      _Pragma("unroll")                                                       \
      for (int tm = 0; tm < 4; tm++)                                          \
        _Pragma("unroll")                                                     \
        for (int tn = 0; tn < 2; tn++)                                        \
          acc[tm][tn] = __builtin_amdgcn_mfma_f32_16x16x32_bf16(af[tm], bfr[tn], acc[tm][tn], 0, 0, 0); \
    }                                                                         \
  }

__global__ __launch_bounds__(512, 4) void gemm_bf16_kernel(
    const bf16* __restrict__ A, const bf16* __restrict__ B,
    const float* __restrict__ bias,
    bf16* __restrict__ Cb, bf16* __restrict__ vTout, float* __restrict__ Cf,
    int N, int K, int swz, long az, long bz, long cz, long biasz, int skipQ)
{
    __shared__ bf16 As0[128 * 64];
    __shared__ bf16 Bs0[128 * 64];
    __shared__ bf16 As1[128 * 64];
    __shared__ bf16 Bs1[128 * 64];

    A += (long)blockIdx.z * az;
    B += (long)blockIdx.z * bz;
    if (Cb) Cb += (long)blockIdx.z * cz;
    if (Cf) Cf += (long)blockIdx.z * cz;
    if (bias) bias += (long)blockIdx.z * biasz;

    const int tid = threadIdx.x;
    const int lane = tid & 63, wave = tid >> 6;   // 8 waves
    const int wm = wave & 1, wn = wave >> 1;      // 2m x 4n

    int bmt, bnt;
    if (swz) {
        const int id = blockIdx.x + gridDim.x * blockIdx.y;
        const int xcd = id & 7, loc = id >> 3;
        bmt = xcd * 8 + (loc & 7);
        bnt = loc >> 3;
    } else {
        bmt = blockIdx.y;
        bnt = blockIdx.x;
    }
    if (skipQ && bnt < 6 && (bmt & 1)) return;

    const long bm = (long)bmt * 128, bn = (long)bnt * 128;
    const int col = lane & 15, quad = lane >> 4;

    f32x4 acc[4][2] = {};

    GEMM_PREF(As0, Bs0, 0);
    for (int kk = 0; kk < K; kk += 128) {
        __syncthreads();
        GEMM_PREF(As1, Bs1, kk + 64);
        GEMM_COMPUTE(As0, Bs0);
        __syncthreads();
        if (kk + 128 < K) GEMM_PREF(As0, Bs0, kk + 128);
        GEMM_COMPUTE(As1, Bs1);
    }

    const bool toVT = (vTout != nullptr) && (bn >= 1536);

    if (toVT) {
        // wave-local 64m x 32n transpose through LDS (4 KB scratch per wave)
        __syncthreads();
        bf16* tb = (wave < 4 ? As0 : Bs0) + (wave & 3) * 2048;
#pragma unroll
        for (int tn = 0; tn < 2; tn++) {
            const int nl = tn * 16 + col;                 // 0..31
            const float bvv = bias[bn + wn * 32 + nl];
#pragma unroll
            for (int tm = 0; tm < 4; tm++) {
                const int mc = tm * 4 + quad;             // 0..15 (4-bf16 m-chunk)
                bf16 t4[4];
#pragma unroll
                for (int r = 0; r < 4; r++)
                    t4[r] = __float2bfloat16(acc[tm][tn][r] + bvv);
                *(uint2*)&tb[(nl * 16 + (mc ^ (nl & 15))) * 4] = *(uint2*)t4;
            }
        }
        const int b_  = (int)((bm + wm * 64) >> 8);
        const int s0  = (int)((bm + wm * 64) & 255);
        const long nb = bn + wn * 32 - 1536;
#pragma unroll
        for (int it2 = 0; it2 < 8; it2++) {
            const int nl = it2 * 4 + quad;                // 0..31
            const uint2 v = *(const uint2*)&tb[(nl * 16 + (col ^ (nl & 15))) * 4];
            *(uint2*)&vTout[((long)b_ * 768 + nb + nl) * 256 + s0 + col * 4] = v;
        }
    } else if (Cf) {
#pragma unroll
        for (int tn = 0; tn < 2; tn++) {
            const long n = bn + wn * 32 + tn * 16 + col;
            const float bvv = bias ? bias[n] : 0.f;
#pragma unroll
            for (int tm = 0; tm < 4; tm++) {
                const long m0 = bm + wm * 64 + tm * 16 + quad * 4;
#pragma unroll
                for (int r = 0; r < 4; r++)
                    Cf[(m0 + r) * N + n] = acc[tm][tn][r] + bvv;
            }
        }
    } else {
#pragma unroll
        for (int tn = 0; tn < 2; tn++) {
            const long n = bn + wn * 32 + tn * 16 + col;
            const float bvv = bias ? bias[n] : 0.f;
#pragma unroll
            for (int tm = 0; tm < 4; tm++) {
                const long m0 = bm + wm * 64 + tm * 16 + quad * 4;
#pragma unroll
                for (int r = 0; r < 4; r++)
                    Cb[(m0 + r) * N + n] = __float2bfloat16(acc[tm][tn][r] + bvv);
            }
        }
    }
}

// ---------------------------------------------------------------------------
// MFMA attention (R3 structure: Ps-halved, 3 blocks/CU, XCD head affinity).
// R5: biasT preloaded into registers at entry (global loads issued beside the
// Q-fragment load, so they complete under the SCORE phases; the post-SCORE
// bias-add is then zero-wait). Same values, same add order -> bit-identical.
// ---------------------------------------------------------------------------
#define PREF_K(DST, JC)                                                      \
  { _Pragma("unroll")                                                        \
    for (int i = 0; i < 4; i++) {                                            \
      const int u = tid + i * 256;                                           \
      const int r = u >> 4, pp = u & 15;                                     \
      const int c = pp ^ (r & 15);                                           \
      ASYNC_COPY16(kbase + ((JC) * 64 + r) * 2304 + c * 8, &DST[u * 8]);     \
    } }

#define PREF_V(DST, KC)                                                      \
  { _Pragma("unroll")                                                        \
    for (int i = 0; i < 3; i++) {                                            \
      const int u = tid + i * 256;                                           \
      const int r = u >> 3, pp = u & 7;                                      \
      const int c = pp ^ (r & 7);                                            \
      ASYNC_COPY16(vbase + r * 256 + (KC) * 64 + c * 8, &DST[u * 8]);        \
    } }

#define SCORE(BUF, JC)                                                       \
  { __builtin_amdgcn_s_setprio(1);                                           \
    _Pragma("unroll")                                                        \
    for (int ks = 0; ks < 3; ks++) {                                         \
      _Pragma("unroll")                                                      \
      for (int jt2 = 0; jt2 < 4; jt2++) {                                    \
        const int row = jt2 * 16 + col;                                      \
        const int c = ks * 4 + quad;                                         \
        const short8 bk_ = *(const short8*)&BUF[row * 128 + ((c ^ (row & 15)) * 8)]; \
        accS[(JC) * 4 + jt2] = __builtin_amdgcn_mfma_f32_16x16x32_bf16(aq[ks], bk_, accS[(JC) * 4 + jt2], 0, 0, 0); \
      } }                                                                     \
    __builtin_amdgcn_s_setprio(0); }

// PC = P-column block (0 or 1) within the current Ps half
#define PV(BUF, PC)                                                          \
  { __builtin_amdgcn_s_setprio(1);                                           \
    _Pragma("unroll")                                                        \
    for (int k2 = 0; k2 < 2; k2++) {                                         \
      const short8 ap = *(const short8*)&Ps[(wave * 16 + col) * PS + (PC) * 64 + k2 * 32 + quad * 8]; \
      _Pragma("unroll")                                                      \
      for (int nt = 0; nt < 6; nt++) {                                       \
        const int row = nt * 16 + col;                                       \
        const int c = k2 * 4 + quad;                                         \
        const short8 bv_ = *(const short8*)&BUF[row * 64 + ((c ^ (row & 7)) * 8)]; \
        accO[nt] = __builtin_amdgcn_mfma_f32_16x16x32_bf16(ap, bv_, accO[nt], 0, 0, 0); \
      } }                                                                     \
    __builtin_amdgcn_s_setprio(0); }

__global__ __launch_bounds__(256, 3) void attn_mfma_kernel(
    const bf16* __restrict__ qkv, const bf16* __restrict__ vT,
    const bf16* __restrict__ biasT, bf16* __restrict__ o)
{
    constexpr int PS = 136;
    __shared__ bf16 Ps[64 * PS];      // 17.0 KB (half of P at a time)
    __shared__ bf16 KV0[64 * 128];    // 16 KB
    __shared__ bf16 KV1[64 * 128];    // 16 KB

    const int blk = blockIdx.x;
    const int h  = blk & 7;           // XCD-affine: one head per XCD
    const int b  = (blk >> 3) & 31;
    const int it = blk >> 8;
    const int i0 = it * 64;
    const int tid = threadIdx.x, lane = tid & 63, wave = tid >> 6;
    const int col = lane & 15, quad = lane >> 4;
    const long rowbase = (long)b * SEQ;

    const bf16* kbase = qkv + rowbase * 2304 + 768 + h * 96;
    const bf16* vbase = vT + ((long)b * 768 + h * 96) * 256;

    PREF_K(KV0, 0);

    short8 aq[3];
    uint2 bias_pre[16];
    {
        const bf16* qrow = qkv + (rowbase + i0 + wave * 16 + col) * 2304 + h * 96;
#pragma unroll
        for (int ks = 0; ks < 3; ks++)
            aq[ks] = *(const short8*)&qrow[ks * 32 + quad * 8];
        const bf16* bbT = biasT + (long)h * SEQ * SEQ + i0 + wave * 16 + quad * 4;
#pragma unroll
        for (int jt = 0; jt < 16; jt++)
            bias_pre[jt] = *(const uint2*)&bbT[(long)(jt * 16 + col) * SEQ];
    }

    f32x4 accS[16] = {};
    __syncthreads();
    PREF_K(KV1, 1);
    SCORE(KV0, 0);
    __syncthreads();
    PREF_K(KV0, 2);
    SCORE(KV1, 1);
    __syncthreads();
    PREF_K(KV1, 3);
    SCORE(KV0, 2);
    __syncthreads();
    PREF_V(KV0, 0);
    SCORE(KV1, 3);

#pragma unroll
    for (int jt = 0; jt < 16; jt++) {
        bf16 b4[4];
        *(uint2*)b4 = bias_pre[jt];
        accS[jt][0] += __bfloat162float(b4[0]);
        accS[jt][1] += __bfloat162float(b4[1]);
        accS[jt][2] += __bfloat162float(b4[2]);
        accS[jt][3] += __bfloat162float(b4[3]);
    }

#pragma unroll
    for (int r = 0; r < 4; r++) {
        float t0 = fmaxf(fmaxf(accS[0][r],  accS[1][r]),  accS[2][r]);
        float t1 = fmaxf(fmaxf(accS[3][r],  accS[4][r]),  accS[5][r]);
        float t2 = fmaxf(fmaxf(accS[6][r],  accS[7][r]),  accS[8][r]);
        float t3 = fmaxf(fmaxf(accS[9][r],  accS[10][r]), accS[11][r]);
        float t4 = fmaxf(fmaxf(accS[12][r], accS[13][r]), accS[14][r]);
        float m  = fmaxf(fmaxf(fmaxf(t0, t1), t2), fmaxf(fmaxf(t3, t4), accS[15][r]));
        for (int d = 1; d < 16; d <<= 1) m = fmaxf(m, __shfl_xor(m, d));
        float s = 0.f;
#pragma unroll
        for (int jt = 0; jt < 16; jt++) {
            const float e = __expf(accS[jt][r] - m);
            accS[jt][r] = e;
            s += e;
        }
        for (int d = 1; d < 16; d <<= 1) s += __shfl_xor(s, d);
        const float inv = __builtin_amdgcn_rcpf(s);
#pragma unroll
        for (int jt = 0; jt < 16; jt++) accS[jt][r] *= inv;
        const int prow = wave * 16 + quad * 4 + r;
#pragma unroll
        for (int jt = 0; jt < 8; jt++)
            Ps[prow * PS + jt * 16 + col] = __float2bfloat16(accS[jt][r]);
    }
    // no barrier for Ps: each wave reads only the rows it wrote

    f32x4 accO[6] = {};
    __syncthreads();
    PREF_V(KV1, 1);
    PV(KV0, 0);
    __syncthreads();
    PREF_V(KV0, 2);
    PV(KV1, 1);
    // overwrite wave-private Ps rows with keys 128..255 (program order per
    // wave guarantees prior PV reads of this region are complete)
#pragma unroll
    for (int r = 0; r < 4; r++) {
        const int prow = wave * 16 + quad * 4 + r;
#pragma unroll
        for (int jt = 8; jt < 16; jt++)
            Ps[prow * PS + (jt - 8) * 16 + col] = __float2bfloat16(accS[jt][r]);
    }
    __syncthreads();
    PREF_V(KV1, 3);
    PV(KV0, 0);                        // keys 128..191
    __syncthreads();
    PV(KV1, 1);                        // keys 192..255

#pragma unroll
    for (int nt = 0; nt < 6; nt++)
#pragma unroll
        for (int r = 0; r < 4; r++) {
            const long m = rowbase + i0 + wave * 16 + quad * 4 + r;
            o[m * DIM + h * 96 + nt * 16 + col] = __float2bfloat16(accO[nt][r]);
        }
}

// out[b, ng*32 + tid>>3] = ob[b*256,:] . Wo5[n,:] + bo5[n]
__global__ __launch_bounds__(256) void final_out_kernel(
    const bf16* __restrict__ ob, const float* __restrict__ Wo5,
    const float* __restrict__ bo5, float* __restrict__ out)
{
    __shared__ float os[768];
    const int b = blockIdx.y, ng = blockIdx.x, tid = threadIdx.x;
    const bf16* orow = ob + (long)b * 256 * 768;
    for (int i = tid; i < 768; i += 256) os[i] = __bfloat162float(orow[i]);
    __syncthreads();

    const int n = ng * 32 + (tid >> 3);
    const int seg = tid & 7;
    const float* wrow = Wo5 + (long)n * 768 + seg * 96;
    const float* xs = &os[seg * 96];
    float s = 0.f;
#pragma unroll
    for (int k = 0; k < 96; k += 4) {
        const float4 w = *(const float4*)&wrow[k];
        s += xs[k] * w.x + xs[k + 1] * w.y + xs[k + 2] * w.z + xs[k + 3] * w.w;
    }
    s += __shfl_xor(s, 1);
    s += __shfl_xor(s, 2);
    s += __shfl_xor(s, 4);
    if (seg == 0) out[b * 768 + n] = s + bo5[n];
}

extern "C" void kernel_launch(void* const* d_in, const int* in_sizes, int n_in,
                              void* d_out, int out_size, void* d_ws, size_t ws_size,
                              hipStream_t stream)
{
    const int*   tokens   = (const int*)d_in[0];
    const float* embed    = (const float*)d_in[1];
    const float* pos_emb  = (const float*)d_in[2];
    const float* pos_q_w  = (const float*)d_in[3];
    const float* pos_q_b  = (const float*)d_in[4];
    const float* pos_k_w  = (const float*)d_in[5];
    const float* pos_k_b  = (const float*)d_in[6];
    const float* pos_ln_g = (const float*)d_in[7];
    const float* pos_ln_b = (const float*)d_in[8];
    const float* rel_tab  = (const float*)d_in[9];
    const int*   rp       = (const int*)d_in[10];
    const float* Wq = (const float*)d_in[11];
    const float* bq = (const float*)d_in[12];
    const float* Wk = (const float*)d_in[13];
    const float* bk = (const float*)d_in[14];
    const float* Wv = (const float*)d_in[15];
    const float* bv = (const float*)d_in[16];
    const float* Wo = (const float*)d_in[17];
    const float* bo = (const float*)d_in[18];
    float* out = (float*)d_out;

    char* p = (char*)d_ws;
    auto alloc = [&](size_t bytes) -> char* {
        char* r = p;
        p += (bytes + 255) & ~(size_t)255;
        return r;
    };
    const long NT = 32L * SEQ;  // 8192

    bf16*  biasT = (bf16*) alloc(8L * SEQ * SEQ * 2);       // [h][j][i] bf16
    bf16*  wlnb  = (bf16*) alloc((long)SEQ * DIM * 2);
    float* pqk   = (float*)alloc(2L * SEQ * DIM * 4);       // pq | pk (f32)
    bf16*  wsWb  = (bf16*) alloc(2L * 768 * 768 * 2);       // posq_w | posk_w bf16
    float* wsB   = (float*)alloc(2L * 768 * 4);
    bf16*  xb    = (bf16*) alloc(NT * DIM * 2);
    bf16*  qkv   = (bf16*) alloc(NT * 2304 * 2);
    bf16*  vT    = (bf16*) alloc(NT * DIM * 2);             // [32][768][256]
    bf16*  ob    = (bf16*) alloc(NT * DIM * 2);
    bf16*  wqkv  = (bf16*) alloc(6L * 2304 * 768 * 2);
    bf16*  woT   = (bf16*) alloc(6L * 768 * 768 * 2);
    bf16*  wf    = (bf16*) alloc(5L * 2304 * 768 * 2);
    float* bqkv  = (float*)alloc(6L * 2304 * 4);
    float* bfus  = (float*)alloc(5L * 2304 * 4);

    const float SCALE = 0.07216878364870322f;   // (HD*2)^-0.5

    // ---- all independent setup in ONE launch ----
    setup_mega_kernel<<<RB_G, 256, 0, stream>>>(
        tokens, embed, pos_emb, pos_q_w, pos_q_b, pos_k_w, pos_k_b,
        pos_ln_g, pos_ln_b, Wq, Wk, Wv, Wo, bq, bk, bv,
        wqkv, woT, bqkv, xb, wlnb, wsWb, wsB, SCALE);

    // Wf_l = Wqkv_{l+1} . Wo_l  (batched, z = l)
    gemm_bf16_kernel<<<dim3(6, 18, 5), 512, 0, stream>>>(
        wqkv + 2304L * 768, woT, nullptr, wf, nullptr, nullptr, 768, 768, 0,
        2304L * 768, 768L * 768, 2304L * 768, 0, 0);
    fused_bias_kernel<<<dim3(72, 5), 256, 0, stream>>>(wqkv, bo, bqkv, bfus);

    // pos projections pq|pk via MFMA (bf16 in, f32 out), z = {q, k}
    gemm_bf16_kernel<<<dim3(6, 2, 2), 512, 0, stream>>>(
        wlnb, wsWb, wsB, nullptr, nullptr, pqk, 768, 768, 0,
        0, 768L * 768, (long)SEQ * DIM, 768, 0);
    // biasT[h][j][i] = SCALE * (pk_j . pq_i) + rel[i,j,h]   (bf16 out)
    gemm_kernel<<<dim3(4, 4, NH), 256, 0, stream>>>(
        pqk + (long)SEQ * DIM, DIM, HD, pqk, DIM, HD, nullptr, 0,
        biasT, SEQ, (long)SEQ * SEQ, SEQ, SEQ, HD, SCALE, rp, rel_tab);

    // ---- layer pipeline ----
    gemm_bf16_kernel<<<dim3(18, 64, 1), 512, 0, stream>>>(
        xb, wqkv, bqkv, qkv, vT, nullptr, 2304, 768, 1, 0, 0, 0, 0, 0);
    for (int l = 0; l < 5; l++) {
        attn_mfma_kernel<<<1024, 256, 0, stream>>>(qkv, vT, biasT, ob);
        gemm_bf16_kernel<<<dim3(18, 64, 1), 512, 0, stream>>>(
            ob, wf + (long)l * 2304 * 768, bfus + (long)l * 2304, qkv, vT, nullptr,
            2304, 768, 1, 0, 0, 0, 0, (l == 4) ? 1 : 0);
    }
    attn_mfma_kernel<<<256, 256, 0, stream>>>(qkv, vT, biasT, ob);   // it=0 only
    final_out_kernel<<<dim3(24, 32), 256, 0, stream>>>(ob, Wo + 5L * 768 * 768, bo + 5L * 768, out);
}

// Round 6
// 629.823 us; speedup vs baseline: 1.0924x; 1.0348x over previous
//
#include <hip/hip_runtime.h>
#include <hip/hip_bf16.h>
#include <math.h>

constexpr int SEQ = 256;
constexpr int DIM = 768;
constexpr int NH  = 8;
constexpr int HD  = 96;

typedef __attribute__((ext_vector_type(8))) short short8;
typedef __attribute__((ext_vector_type(4))) float f32x4;
using bf16 = __hip_bfloat16;

#define ASYNC_COPY16(gptr, lptr) \
  __builtin_amdgcn_global_load_lds((const __attribute__((address_space(1))) void*)(gptr), \
                                   (__attribute__((address_space(3))) void*)(lptr), 16, 0, 0)

// ---------------------------------------------------------------------------
// f32 tiled GEMM (biasT producer only): value(j=m, i=n) = acc*scale +
// rtab[rp[i*256+j]*8+h]. R6: output scattered into the attn-lane layout
// biasTp[(h*16 + it*4 + wave)*4096 + jt*256 + lane*4 + r] so the attention
// kernel's bias read is lane-coalesced (same values, reordered only).
//   i = it*64 + wave*16 + quad*4 + r ; j = jt*16 + col ; lane = quad*16+col
// ---------------------------------------------------------------------------
__global__ __launch_bounds__(256) void gemm_kernel(
    const float* __restrict__ A, int lda, long aoz,
    const float* __restrict__ W, int ldw, long woz,
    const float* __restrict__ bias, long boz,
    bf16* __restrict__ C, int ldc, long coz,
    int M, int N, int K, float scale,
    const int* __restrict__ rp, const float* __restrict__ rtab)
{
    const int hz = blockIdx.z;
    A += (long)hz * aoz;
    W += (long)hz * woz;
    if (bias) bias += (long)hz * boz;
    C += (long)hz * coz;

    __shared__ float As[16][68];
    __shared__ float Ws[16][68];

    const int bm = blockIdx.y * 64;
    const int bn = blockIdx.x * 64;
    const int tid = threadIdx.x;
    const int tx = tid & 15;
    const int ty = tid >> 4;

    float acc[4][4] = {};

    for (int k0 = 0; k0 < K; k0 += 16) {
#pragma unroll
        for (int i = 0; i < 4; i++) {
            int idx = tid + i * 256;
            int r = idx >> 4, c = idx & 15;
            As[c][r] = A[(long)(bm + r) * lda + (k0 + c)];
            Ws[c][r] = W[(long)(bn + r) * ldw + (k0 + c)];
        }
        __syncthreads();
#pragma unroll
        for (int kk = 0; kk < 16; kk++) {
            const float4 a = *(const float4*)&As[kk][ty * 4];
            const float4 w = *(const float4*)&Ws[kk][tx * 4];
            acc[0][0] += a.x * w.x; acc[0][1] += a.x * w.y; acc[0][2] += a.x * w.z; acc[0][3] += a.x * w.w;
            acc[1][0] += a.y * w.x; acc[1][1] += a.y * w.y; acc[1][2] += a.y * w.z; acc[1][3] += a.y * w.w;
            acc[2][0] += a.z * w.x; acc[2][1] += a.z * w.y; acc[2][2] += a.z * w.z; acc[2][3] += a.z * w.w;
            acc[3][0] += a.w * w.x; acc[3][1] += a.w * w.y; acc[3][2] += a.w * w.z; acc[3][3] += a.w * w.w;
        }
        __syncthreads();
    }

    const int n0 = bn + tx * 4;
    float4 bv = make_float4(0.f, 0.f, 0.f, 0.f);
    if (bias) bv = *(const float4*)&bias[n0];
#pragma unroll
    for (int i = 0; i < 4; i++) {
        const int m = bm + ty * 4 + i;
        float4 r;
        if (rtab) {
            r.x = acc[i][0] * scale + rtab[rp[(n0 + 0) * 256 + m] * 8 + hz];
            r.y = acc[i][1] * scale + rtab[rp[(n0 + 1) * 256 + m] * 8 + hz];
            r.z = acc[i][2] * scale + rtab[rp[(n0 + 2) * 256 + m] * 8 + hz];
            r.w = acc[i][3] * scale + rtab[rp[(n0 + 3) * 256 + m] * 8 + hz];
        } else {
            r.x = (acc[i][0] + bv.x) * scale;
            r.y = (acc[i][1] + bv.y) * scale;
            r.z = (acc[i][2] + bv.z) * scale;
            r.w = (acc[i][3] + bv.w) * scale;
        }
        bf16 t4[4];
        t4[0] = __float2bfloat16(r.x);
        t4[1] = __float2bfloat16(r.y);
        t4[2] = __float2bfloat16(r.z);
        t4[3] = __float2bfloat16(r.w);
        if (rtab) {
            // attn-lane layout: it=bx, wave=tx>>2, quad=tx&3, jt=by*4+(ty>>2)
            bf16* dst = C + ((long)blockIdx.x * 4 + (tx >> 2)) * 4096
                          + ((long)blockIdx.y * 4 + (ty >> 2)) * 256;
            const int lane2 = (tx & 3) * 16 + ((ty * 4 + i) & 15);
            *(uint2*)&dst[lane2 * 4] = *(uint2*)t4;
        } else {
            *(uint2*)&C[(long)m * ldc + n0] = *(uint2*)t4;
        }
    }
}

// ---------------------------------------------------------------------------
// Setup mega-kernel (role by blockIdx ranges)
// ---------------------------------------------------------------------------
constexpr int RB_A = 10368;
constexpr int RB_B = RB_A + 3456;
constexpr int RB_C = RB_B + 54;
constexpr int RB_D = RB_C + 6144;   // packed: 8192 rows x 192 f32x4 units
constexpr int RB_E = RB_D + 256;
constexpr int RB_F = RB_E + 1152;
constexpr int RB_G = RB_F + 2;

__global__ __launch_bounds__(256) void setup_mega_kernel(
    const int* __restrict__ tokens, const float* __restrict__ embed,
    const float* __restrict__ pos_emb,
    const float* __restrict__ pos_q_w, const float* __restrict__ pos_q_b,
    const float* __restrict__ pos_k_w, const float* __restrict__ pos_k_b,
    const float* __restrict__ pos_ln_g, const float* __restrict__ pos_ln_b,
    const float* __restrict__ Wq, const float* __restrict__ Wk,
    const float* __restrict__ Wv, const float* __restrict__ Wo,
    const float* __restrict__ bq, const float* __restrict__ bk,
    const float* __restrict__ bv,
    bf16* __restrict__ wqkv, bf16* __restrict__ woT, float* __restrict__ bqkv,
    bf16* __restrict__ xb, bf16* __restrict__ wln,
    bf16* __restrict__ wsW, float* __restrict__ wsB, float scale)
{
    const int bid = blockIdx.x, tid = threadIdx.x;

    if (bid < RB_A) {
        const long idx = (long)bid * 256 + tid;
        const long e = idx * 4;
        const int k = (int)(e % 768);
        const long nl = e / 768;
        const int n = (int)(nl % 2304);
        const int l = (int)(nl / 2304);
        const float* src;
        float sc = 1.f;
        if (n < 768)       { src = Wq + ((long)l * 768 + n) * 768; sc = scale; }
        else if (n < 1536) { src = Wk + ((long)l * 768 + (n - 768)) * 768; }
        else               { src = Wv + ((long)l * 768 + (n - 1536)) * 768; }
        const float4 v = *(const float4*)&src[k];
        bf16 tmp[4];
        tmp[0] = __float2bfloat16(v.x * sc);
        tmp[1] = __float2bfloat16(v.y * sc);
        tmp[2] = __float2bfloat16(v.z * sc);
        tmp[3] = __float2bfloat16(v.w * sc);
        *(uint2*)&wqkv[((long)l * 2304 + n) * 768 + k] = *(uint2*)tmp;
    } else if (bid < RB_B) {
        __shared__ float t[32][33];
        const int b2 = bid - RB_A;
        const int l = b2 / 576, r2 = b2 % 576;
        const int c0 = (r2 % 24) * 32, j0 = (r2 / 24) * 32;
        const int tx = tid & 31, ty = tid >> 5;
        const float* src = Wo + (long)l * 768 * 768;
#pragma unroll
        for (int rr = 0; rr < 32; rr += 8)
            t[ty + rr][tx] = src[(long)(c0 + ty + rr) * 768 + j0 + tx];
        __syncthreads();
        bf16* dst = woT + (long)l * 768 * 768;
#pragma unroll
        for (int rr = 0; rr < 32; rr += 8)
            dst[(long)(j0 + ty + rr) * 768 + c0 + tx] = __float2bfloat16(t[tx][ty + rr]);
    } else if (bid < RB_C) {
        const int idx = (bid - RB_B) * 256 + tid;
        if (idx < 6 * 2304) {
            const int n = idx % 2304, l = idx / 2304;
            float v;
            if (n < 768)       v = bq[l * 768 + n] * scale;
            else if (n < 1536) v = bk[l * 768 + (n - 768)];
            else               v = bv[l * 768 + (n - 1536)];
            bqkv[idx] = v;
        }
    } else if (bid < RB_D) {
        const int idx = (bid - RB_C) * 256 + tid;   // < 8192*192
        const int t = idx / 192;
        const int d = idx - t * 192;
        const int tok = tokens[t];
        const float4 v = ((const float4*)(embed + (long)tok * DIM))[d];
        bf16 tmp[4];
        tmp[0] = __float2bfloat16(v.x);
        tmp[1] = __float2bfloat16(v.y);
        tmp[2] = __float2bfloat16(v.z);
        tmp[3] = __float2bfloat16(v.w);
        *(uint2*)&xb[(long)t * DIM + d * 4] = *(uint2*)tmp;
    } else if (bid < RB_E) {
        __shared__ float buf[256];
        const int i = bid - RB_D;
        const float* row = pos_emb + (long)i * DIM;
        float v0 = row[tid], v1 = row[tid + 256], v2 = row[tid + 512];
        buf[tid] = v0 + v1 + v2;
        __syncthreads();
        for (int off = 128; off > 0; off >>= 1) {
            if (tid < off) buf[tid] += buf[tid + off];
            __syncthreads();
        }
        const float mean = buf[0] * (1.f / 768.f);
        __syncthreads();
        const float d0 = v0 - mean, d1 = v1 - mean, d2 = v2 - mean;
        buf[tid] = d0 * d0 + d1 * d1 + d2 * d2;
        __syncthreads();
        for (int off = 128; off > 0; off >>= 1) {
            if (tid < off) buf[tid] += buf[tid + off];
            __syncthreads();
        }
        const float rstd = rsqrtf(buf[0] * (1.f / 768.f) + 1e-5f);
        bf16* wr = wln + (long)i * DIM;
        wr[tid]       = __float2bfloat16(d0 * rstd * pos_ln_g[tid]       + pos_ln_b[tid]);
        wr[tid + 256] = __float2bfloat16(d1 * rstd * pos_ln_g[tid + 256] + pos_ln_b[tid + 256]);
        wr[tid + 512] = __float2bfloat16(d2 * rstd * pos_ln_g[tid + 512] + pos_ln_b[tid + 512]);
    } else if (bid < RB_F) {
        const long idx = (long)(bid - RB_E) * 256 + tid;
        const long e = idx * 4;
        const float4 v = (e < 589824) ? *(const float4*)&pos_q_w[e]
                                      : *(const float4*)&pos_k_w[e - 589824];
        bf16 tmp[4];
        tmp[0] = __float2bfloat16(v.x);
        tmp[1] = __float2bfloat16(v.y);
        tmp[2] = __float2bfloat16(v.z);
        tmp[3] = __float2bfloat16(v.w);
        *(uint2*)&wsW[e] = *(uint2*)tmp;
    } else {
        const int idx = (bid - RB_F) * 256 + tid;
        wsB[idx] = (idx < 768) ? pos_q_b[idx] : pos_k_b[idx - 768];
    }
}

// bf[l][n] = wqkv[l+1][n,:] . bo[l] + bqkv[l+1][n]   (l = 0..4)
__global__ __launch_bounds__(256) void fused_bias_kernel(
    const bf16* __restrict__ wqkv, const float* __restrict__ bo,
    const float* __restrict__ bqkv, float* __restrict__ bf_)
{
    const int l = blockIdx.y;
    const int lane = threadIdx.x & 63, wave = threadIdx.x >> 6;
    const int nloc = wave * 8 + (lane >> 3);
    const int seg = lane & 7;
    const int n = blockIdx.x * 32 + nloc;
    const bf16* wrow = wqkv + ((long)(l + 1) * 2304 + n) * 768 + seg * 96;
    const float* bsrc = bo + (long)l * 768 + seg * 96;
    float s = 0.f;
#pragma unroll
    for (int c8 = 0; c8 < 12; c8++) {
        const short8 w8 = *(const short8*)&wrow[c8 * 8];
#pragma unroll
        for (int e = 0; e < 8; e++) {
            bf16 b;
            *(short*)&b = w8[e];
            s += __bfloat162float(b) * bsrc[c8 * 8 + e];
        }
    }
    s += __shfl_xor(s, 1);
    s += __shfl_xor(s, 2);
    s += __shfl_xor(s, 4);
    if (seg == 0) bf_[l * 2304 + n] = s + bqkv[(l + 1) * 2304 + n];
}

// ---------------------------------------------------------------------------
// bf16 MFMA GEMM: 128x128 tile, BK=64, ping-pong double-buffered LDS.
// Cf != null: write f32 output (used for pos projections pq|pk).
// ---------------------------------------------------------------------------
#define GEMM_PREF(AS, BS, KB)                                                 \
  {                                                                           \
    _Pragma("unroll")                                                         \
    for (int i = 0; i < 2; i++) {                                             \
      const int u = tid + i * 512;                                            \
      const int r = u >> 3, c = u & 7;                                        \
      const int ca = c ^ (r & 7);                                             \
      ASYNC_COPY16(A + (bm + r) * (long)K + (KB) + ca * 8, &AS[u * 8]);       \
      ASYNC_COPY16(B + (bn + r) * (long)K + (KB) + ca * 8, &BS[u * 8]);       \
    }                                                                         \
  }

#define GEMM_COMPUTE(AS, BS)                                                  \
  {                                                                           \
    _Pragma("unroll")                                                         \
    for (int ks = 0; ks < 2; ks++) {                                          \
      const int cc = ks * 4 + quad;                                           \
      short8 af[4], bfr[2];                                                   \
      _Pragma("unroll")                                                       \
      for (int t = 0; t < 4; t++) {                                           \
        const int ra = wm * 64 + t * 16 + col;                                \
        af[t] = *(const short8*)&AS[ra * 64 + ((cc ^ (ra & 7)) * 8)];         \
      }                                                                       \
      _Pragma("unroll")                                                       \
      for (int t = 0; t < 2; t++) {                                           \
        const int rb = wn * 32 + t * 16 + col;                                \
        bfr[t] = *(const short8*)&BS[rb * 64 + ((cc ^ (rb & 7)) * 8)];        \
      }                                                                       \
      _Pragma("unroll")                                                       \
      for (int tm = 0; tm < 4; tm++)                                          \
        _Pragma("unroll")                                                     \
        for (int tn = 0; tn < 2; tn++)                                        \
          acc[tm][tn] = __builtin_amdgcn_mfma_f32_16x16x32_bf16(af[tm], bfr[tn], acc[tm][tn], 0, 0, 0); \
    }                                                                         \
  }

__global__ __launch_bounds__(512, 4) void gemm_bf16_kernel(
    const bf16* __restrict__ A, const bf16* __restrict__ B,
    const float* __restrict__ bias,
    bf16* __restrict__ Cb, bf16* __restrict__ vTout, float* __restrict__ Cf,
    int N, int K, int swz, long az, long bz, long cz, long biasz, int skipQ)
{
    __shared__ bf16 As0[128 * 64];
    __shared__ bf16 Bs0[128 * 64];
    __shared__ bf16 As1[128 * 64];
    __shared__ bf16 Bs1[128 * 64];

    A += (long)blockIdx.z * az;
    B += (long)blockIdx.z * bz;
    if (Cb) Cb += (long)blockIdx.z * cz;
    if (Cf) Cf += (long)blockIdx.z * cz;
    if (bias) bias += (long)blockIdx.z * biasz;

    const int tid = threadIdx.x;
    const int lane = tid & 63, wave = tid >> 6;   // 8 waves
    const int wm = wave & 1, wn = wave >> 1;      // 2m x 4n

    int bmt, bnt;
    if (swz) {
        const int id = blockIdx.x + gridDim.x * blockIdx.y;
        const int xcd = id & 7, loc = id >> 3;
        bmt = xcd * 8 + (loc & 7);
        bnt = loc >> 3;
    } else {
        bmt = blockIdx.y;
        bnt = blockIdx.x;
    }
    if (skipQ && bnt < 6 && (bmt & 1)) return;

    const long bm = (long)bmt * 128, bn = (long)bnt * 128;
    const int col = lane & 15, quad = lane >> 4;

    f32x4 acc[4][2] = {};

    GEMM_PREF(As0, Bs0, 0);
    for (int kk = 0; kk < K; kk += 128) {
        __syncthreads();
        GEMM_PREF(As1, Bs1, kk + 64);
        GEMM_COMPUTE(As0, Bs0);
        __syncthreads();
        if (kk + 128 < K) GEMM_PREF(As0, Bs0, kk + 128);
        GEMM_COMPUTE(As1, Bs1);
    }

    const bool toVT = (vTout != nullptr) && (bn >= 1536);

    if (toVT) {
        // wave-local 64m x 32n transpose through LDS (4 KB scratch per wave)
        __syncthreads();
        bf16* tb = (wave < 4 ? As0 : Bs0) + (wave & 3) * 2048;
#pragma unroll
        for (int tn = 0; tn < 2; tn++) {
            const int nl = tn * 16 + col;                 // 0..31
            const float bvv = bias[bn + wn * 32 + nl];
#pragma unroll
            for (int tm = 0; tm < 4; tm++) {
                const int mc = tm * 4 + quad;             // 0..15 (4-bf16 m-chunk)
                bf16 t4[4];
#pragma unroll
                for (int r = 0; r < 4; r++)
                    t4[r] = __float2bfloat16(acc[tm][tn][r] + bvv);
                *(uint2*)&tb[(nl * 16 + (mc ^ (nl & 15))) * 4] = *(uint2*)t4;
            }
        }
        const int b_  = (int)((bm + wm * 64) >> 8);
        const int s0  = (int)((bm + wm * 64) & 255);
        const long nb = bn + wn * 32 - 1536;
#pragma unroll
        for (int it2 = 0; it2 < 8; it2++) {
            const int nl = it2 * 4 + quad;                // 0..31
            const uint2 v = *(const uint2*)&tb[(nl * 16 + (col ^ (nl & 15))) * 4];
            *(uint2*)&vTout[((long)b_ * 768 + nb + nl) * 256 + s0 + col * 4] = v;
        }
    } else if (Cf) {
#pragma unroll
        for (int tn = 0; tn < 2; tn++) {
            const long n = bn + wn * 32 + tn * 16 + col;
            const float bvv = bias ? bias[n] : 0.f;
#pragma unroll
            for (int tm = 0; tm < 4; tm++) {
                const long m0 = bm + wm * 64 + tm * 16 + quad * 4;
#pragma unroll
                for (int r = 0; r < 4; r++)
                    Cf[(m0 + r) * N + n] = acc[tm][tn][r] + bvv;
            }
        }
    } else {
#pragma unroll
        for (int tn = 0; tn < 2; tn++) {
            const long n = bn + wn * 32 + tn * 16 + col;
            const float bvv = bias ? bias[n] : 0.f;
#pragma unroll
            for (int tm = 0; tm < 4; tm++) {
                const long m0 = bm + wm * 64 + tm * 16 + quad * 4;
#pragma unroll
                for (int r = 0; r < 4; r++)
                    Cb[(m0 + r) * N + n] = __float2bfloat16(acc[tm][tn][r] + bvv);
            }
        }
    }
}

// ---------------------------------------------------------------------------
// MFMA attention (R3 structure: Ps-halved, 3 blocks/CU, XCD head affinity).
// R6: bias read post-SCORE (R3 position) but from the lane-coalesced biasTp
// layout: wave reads 16 x contiguous 512B (one uint2 per lane per jt).
// ---------------------------------------------------------------------------
#define PREF_K(DST, JC)                                                      \
  { _Pragma("unroll")                                                        \
    for (int i = 0; i < 4; i++) {                                            \
      const int u = tid + i * 256;                                           \
      const int r = u >> 4, pp = u & 15;                                     \
      const int c = pp ^ (r & 15);                                           \
      ASYNC_COPY16(kbase + ((JC) * 64 + r) * 2304 + c * 8, &DST[u * 8]);     \
    } }

#define PREF_V(DST, KC)                                                      \
  { _Pragma("unroll")                                                        \
    for (int i = 0; i < 3; i++) {                                            \
      const int u = tid + i * 256;                                           \
      const int r = u >> 3, pp = u & 7;                                      \
      const int c = pp ^ (r & 7);                                            \
      ASYNC_COPY16(vbase + r * 256 + (KC) * 64 + c * 8, &DST[u * 8]);        \
    } }

#define SCORE(BUF, JC)                                                       \
  { __builtin_amdgcn_s_setprio(1);                                           \
    _Pragma("unroll")                                                        \
    for (int ks = 0; ks < 3; ks++) {                                         \
      _Pragma("unroll")                                                      \
      for (int jt2 = 0; jt2 < 4; jt2++) {                                    \
        const int row = jt2 * 16 + col;                                      \
        const int c = ks * 4 + quad;                                         \
        const short8 bk_ = *(const short8*)&BUF[row * 128 + ((c ^ (row & 15)) * 8)]; \
        accS[(JC) * 4 + jt2] = __builtin_amdgcn_mfma_f32_16x16x32_bf16(aq[ks], bk_, accS[(JC) * 4 + jt2], 0, 0, 0); \
      } }                                                                     \
    __builtin_amdgcn_s_setprio(0); }

// PC = P-column block (0 or 1) within the current Ps half
#define PV(BUF, PC)                                                          \
  { __builtin_amdgcn_s_setprio(1);                                           \
    _Pragma("unroll")                                                        \
    for (int k2 = 0; k2 < 2; k2++) {                                         \
      const short8 ap = *(const short8*)&Ps[(wave * 16 + col) * PS + (PC) * 64 + k2 * 32 + quad * 8]; \
      _Pragma("unroll")                                                      \
      for (int nt = 0; nt < 6; nt++) {                                       \
        const int row = nt * 16 + col;                                       \
        const int c = k2 * 4 + quad;                                         \
        const short8 bv_ = *(const short8*)&BUF[row * 64 + ((c ^ (row & 7)) * 8)]; \
        accO[nt] = __builtin_amdgcn_mfma_f32_16x16x32_bf16(ap, bv_, accO[nt], 0, 0, 0); \
      } }                                                                     \
    __builtin_amdgcn_s_setprio(0); }

__global__ __launch_bounds__(256, 3) void attn_mfma_kernel(
    const bf16* __restrict__ qkv, const bf16* __restrict__ vT,
    const bf16* __restrict__ biasTp, bf16* __restrict__ o)
{
    constexpr int PS = 136;
    __shared__ bf16 Ps[64 * PS];      // 17.0 KB (half of P at a time)
    __shared__ bf16 KV0[64 * 128];    // 16 KB
    __shared__ bf16 KV1[64 * 128];    // 16 KB

    const int blk = blockIdx.x;
    const int h  = blk & 7;           // XCD-affine: one head per XCD
    const int b  = (blk >> 3) & 31;
    const int it = blk >> 8;
    const int i0 = it * 64;
    const int tid = threadIdx.x, lane = tid & 63, wave = tid >> 6;
    const int col = lane & 15, quad = lane >> 4;
    const long rowbase = (long)b * SEQ;

    const bf16* kbase = qkv + rowbase * 2304 + 768 + h * 96;
    const bf16* vbase = vT + ((long)b * 768 + h * 96) * 256;

    PREF_K(KV0, 0);

    short8 aq[3];
    {
        const bf16* qrow = qkv + (rowbase + i0 + wave * 16 + col) * 2304 + h * 96;
#pragma unroll
        for (int ks = 0; ks < 3; ks++)
            aq[ks] = *(const short8*)&qrow[ks * 32 + quad * 8];
    }

    f32x4 accS[16] = {};
    __syncthreads();
    PREF_K(KV1, 1);
    SCORE(KV0, 0);
    __syncthreads();
    PREF_K(KV0, 2);
    SCORE(KV1, 1);
    __syncthreads();
    PREF_K(KV1, 3);
    SCORE(KV0, 2);
    __syncthreads();
    PREF_V(KV0, 0);
    SCORE(KV1, 3);

    // lane-coalesced bias: wave's 8KB block, 512B contiguous per jt
    {
        const bf16* bbT = biasTp + ((long)(h * 16 + it * 4 + wave) * 4096) + lane * 4;
#pragma unroll
        for (int jt = 0; jt < 16; jt++) {
            bf16 b4[4];
            *(uint2*)b4 = *(const uint2*)&bbT[jt * 256];
            accS[jt][0] += __bfloat162float(b4[0]);
            accS[jt][1] += __bfloat162float(b4[1]);
            accS[jt][2] += __bfloat162float(b4[2]);
            accS[jt][3] += __bfloat162float(b4[3]);
        }
    }

#pragma unroll
    for (int r = 0; r < 4; r++) {
        float t0 = fmaxf(fmaxf(accS[0][r],  accS[1][r]),  accS[2][r]);
        float t1 = fmaxf(fmaxf(accS[3][r],  accS[4][r]),  accS[5][r]);
        float t2 = fmaxf(fmaxf(accS[6][r],  accS[7][r]),  accS[8][r]);
        float t3 = fmaxf(fmaxf(accS[9][r],  accS[10][r]), accS[11][r]);
        float t4 = fmaxf(fmaxf(accS[12][r], accS[13][r]), accS[14][r]);
        float m  = fmaxf(fmaxf(fmaxf(t0, t1), t2), fmaxf(fmaxf(t3, t4), accS[15][r]));
        for (int d = 1; d < 16; d <<= 1) m = fmaxf(m, __shfl_xor(m, d));
        float s = 0.f;
#pragma unroll
        for (int jt = 0; jt < 16; jt++) {
            const float e = __expf(accS[jt][r] - m);
            accS[jt][r] = e;
            s += e;
        }
        for (int d = 1; d < 16; d <<= 1) s += __shfl_xor(s, d);
        const float inv = __builtin_amdgcn_rcpf(s);
#pragma unroll
        for (int jt = 0; jt < 16; jt++) accS[jt][r] *= inv;
        const int prow = wave * 16 + quad * 4 + r;
#pragma unroll
        for (int jt = 0; jt < 8; jt++)
            Ps[prow * PS + jt * 16 + col] = __float2bfloat16(accS[jt][r]);
    }
    // no barrier for Ps: each wave reads only the rows it wrote

    f32x4 accO[6] = {};
    __syncthreads();
    PREF_V(KV1, 1);
    PV(KV0, 0);
    __syncthreads();
    PREF_V(KV0, 2);
    PV(KV1, 1);
    // overwrite wave-private Ps rows with keys 128..255 (program order per
    // wave guarantees prior PV reads of this region are complete)
#pragma unroll
    for (int r = 0; r < 4; r++) {
        const int prow = wave * 16 + quad * 4 + r;
#pragma unroll
        for (int jt = 8; jt < 16; jt++)
            Ps[prow * PS + (jt - 8) * 16 + col] = __float2bfloat16(accS[jt][r]);
    }
    __syncthreads();
    PREF_V(KV1, 3);
    PV(KV0, 0);                        // keys 128..191
    __syncthreads();
    PV(KV1, 1);                        // keys 192..255

#pragma unroll
    for (int nt = 0; nt < 6; nt++)
#pragma unroll
        for (int r = 0; r < 4; r++) {
            const long m = rowbase + i0 + wave * 16 + quad * 4 + r;
            o[m * DIM + h * 96 + nt * 16 + col] = __float2bfloat16(accO[nt][r]);
        }
}

// out[b, ng*32 + tid>>3] = ob[b*256,:] . Wo5[n,:] + bo5[n]
__global__ __launch_bounds__(256) void final_out_kernel(
    const bf16* __restrict__ ob, const float* __restrict__ Wo5,
    const float* __restrict__ bo5, float* __restrict__ out)
{
    __shared__ float os[768];
    const int b = blockIdx.y, ng = blockIdx.x, tid = threadIdx.x;
    const bf16* orow = ob + (long)b * 256 * 768;
    for (int i = tid; i < 768; i += 256) os[i] = __bfloat162float(orow[i]);
    __syncthreads();

    const int n = ng * 32 + (tid >> 3);
    const int seg = tid & 7;
    const float* wrow = Wo5 + (long)n * 768 + seg * 96;
    const float* xs = &os[seg * 96];
    float s = 0.f;
#pragma unroll
    for (int k = 0; k < 96; k += 4) {
        const float4 w = *(const float4*)&wrow[k];
        s += xs[k] * w.x + xs[k + 1] * w.y + xs[k + 2] * w.z + xs[k + 3] * w.w;
    }
    s += __shfl_xor(s, 1);
    s += __shfl_xor(s, 2);
    s += __shfl_xor(s, 4);
    if (seg == 0) out[b * 768 + n] = s + bo5[n];
}

extern "C" void kernel_launch(void* const* d_in, const int* in_sizes, int n_in,
                              void* d_out, int out_size, void* d_ws, size_t ws_size,
                              hipStream_t stream)
{
    const int*   tokens   = (const int*)d_in[0];
    const float* embed    = (const float*)d_in[1];
    const float* pos_emb  = (const float*)d_in[2];
    const float* pos_q_w  = (const float*)d_in[3];
    const float* pos_q_b  = (const float*)d_in[4];
    const float* pos_k_w  = (const float*)d_in[5];
    const float* pos_k_b  = (const float*)d_in[6];
    const float* pos_ln_g = (const float*)d_in[7];
    const float* pos_ln_b = (const float*)d_in[8];
    const float* rel_tab  = (const float*)d_in[9];
    const int*   rp       = (const int*)d_in[10];
    const float* Wq = (const float*)d_in[11];
    const float* bq = (const float*)d_in[12];
    const float* Wk = (const float*)d_in[13];
    const float* bk = (const float*)d_in[14];
    const float* Wv = (const float*)d_in[15];
    const float* bv = (const float*)d_in[16];
    const float* Wo = (const float*)d_in[17];
    const float* bo = (const float*)d_in[18];
    float* out = (float*)d_out;

    char* p = (char*)d_ws;
    auto alloc = [&](size_t bytes) -> char* {
        char* r = p;
        p += (bytes + 255) & ~(size_t)255;
        return r;
    };
    const long NT = 32L * SEQ;  // 8192

    bf16*  biasT = (bf16*) alloc(8L * SEQ * SEQ * 2);       // lane-layout bf16
    bf16*  wlnb  = (bf16*) alloc((long)SEQ * DIM * 2);
    float* pqk   = (float*)alloc(2L * SEQ * DIM * 4);       // pq | pk (f32)
    bf16*  wsWb  = (bf16*) alloc(2L * 768 * 768 * 2);       // posq_w | posk_w bf16
    float* wsB   = (float*)alloc(2L * 768 * 4);
    bf16*  xb    = (bf16*) alloc(NT * DIM * 2);
    bf16*  qkv   = (bf16*) alloc(NT * 2304 * 2);
    bf16*  vT    = (bf16*) alloc(NT * DIM * 2);             // [32][768][256]
    bf16*  ob    = (bf16*) alloc(NT * DIM * 2);
    bf16*  wqkv  = (bf16*) alloc(6L * 2304 * 768 * 2);
    bf16*  woT   = (bf16*) alloc(6L * 768 * 768 * 2);
    bf16*  wf    = (bf16*) alloc(5L * 2304 * 768 * 2);
    float* bqkv  = (float*)alloc(6L * 2304 * 4);
    float* bfus  = (float*)alloc(5L * 2304 * 4);

    const float SCALE = 0.07216878364870322f;   // (HD*2)^-0.5

    // ---- all independent setup in ONE launch ----
    setup_mega_kernel<<<RB_G, 256, 0, stream>>>(
        tokens, embed, pos_emb, pos_q_w, pos_q_b, pos_k_w, pos_k_b,
        pos_ln_g, pos_ln_b, Wq, Wk, Wv, Wo, bq, bk, bv,
        wqkv, woT, bqkv, xb, wlnb, wsWb, wsB, SCALE);

    // Wf_l = Wqkv_{l+1} . Wo_l  (batched, z = l)
    gemm_bf16_kernel<<<dim3(6, 18, 5), 512, 0, stream>>>(
        wqkv + 2304L * 768, woT, nullptr, wf, nullptr, nullptr, 768, 768, 0,
        2304L * 768, 768L * 768, 2304L * 768, 0, 0);
    fused_bias_kernel<<<dim3(72, 5), 256, 0, stream>>>(wqkv, bo, bqkv, bfus);

    // pos projections pq|pk via MFMA (bf16 in, f32 out), z = {q, k}
    gemm_bf16_kernel<<<dim3(6, 2, 2), 512, 0, stream>>>(
        wlnb, wsWb, wsB, nullptr, nullptr, pqk, 768, 768, 0,
        0, 768L * 768, (long)SEQ * DIM, 768, 0);
    // biasTp (lane layout) = SCALE * (pk_j . pq_i) + rel[i,j,h]
    gemm_kernel<<<dim3(4, 4, NH), 256, 0, stream>>>(
        pqk + (long)SEQ * DIM, DIM, HD, pqk, DIM, HD, nullptr, 0,
        biasT, SEQ, (long)SEQ * SEQ, SEQ, SEQ, HD, SCALE, rp, rel_tab);

    // ---- layer pipeline ----
    gemm_bf16_kernel<<<dim3(18, 64, 1), 512, 0, stream>>>(
        xb, wqkv, bqkv, qkv, vT, nullptr, 2304, 768, 1, 0, 0, 0, 0, 0);
    for (int l = 0; l < 5; l++) {
        attn_mfma_kernel<<<1024, 256, 0, stream>>>(qkv, vT, biasT, ob);
        gemm_bf16_kernel<<<dim3(18, 64, 1), 512, 0, stream>>>(
            ob, wf + (long)l * 2304 * 768, bfus + (long)l * 2304, qkv, vT, nullptr,
            2304, 768, 1, 0, 0, 0, 0, (l == 4) ? 1 : 0);
    }
    attn_mfma_kernel<<<256, 256, 0, stream>>>(qkv, vT, biasT, ob);   // it=0 only
    final_out_kernel<<<dim3(24, 32), 256, 0, stream>>>(ob, Wo + 5L * 768 * 768, bo + 5L * 768, out);
}

// Round 7
// 603.512 us; speedup vs baseline: 1.1400x; 1.0436x over previous
//
#include <hip/hip_runtime.h>
#include <hip/hip_bf16.h>
#include <math.h>

constexpr int SEQ = 256;
constexpr int DIM = 768;
constexpr int NH  = 8;
constexpr int HD  = 96;

typedef __attribute__((ext_vector_type(8))) short short8;
typedef __attribute__((ext_vector_type(4))) float f32x4;
using bf16 = __hip_bfloat16;

#define ASYNC_COPY16(gptr, lptr) \
  __builtin_amdgcn_global_load_lds((const __attribute__((address_space(1))) void*)(gptr), \
                                   (__attribute__((address_space(3))) void*)(lptr), 16, 0, 0)

// ---------------------------------------------------------------------------
// f32 tiled GEMM (biasT producer only): output scattered into attn-lane layout
// biasTp[(h*16 + it*4 + wave)*4096 + jt*256 + lane*4 + r]  (verified R6).
// ---------------------------------------------------------------------------
__global__ __launch_bounds__(256) void gemm_kernel(
    const float* __restrict__ A, int lda, long aoz,
    const float* __restrict__ W, int ldw, long woz,
    const float* __restrict__ bias, long boz,
    bf16* __restrict__ C, int ldc, long coz,
    int M, int N, int K, float scale,
    const int* __restrict__ rp, const float* __restrict__ rtab)
{
    const int hz = blockIdx.z;
    A += (long)hz * aoz;
    W += (long)hz * woz;
    if (bias) bias += (long)hz * boz;
    C += (long)hz * coz;

    __shared__ float As[16][68];
    __shared__ float Ws[16][68];

    const int bm = blockIdx.y * 64;
    const int bn = blockIdx.x * 64;
    const int tid = threadIdx.x;
    const int tx = tid & 15;
    const int ty = tid >> 4;

    float acc[4][4] = {};

    for (int k0 = 0; k0 < K; k0 += 16) {
#pragma unroll
        for (int i = 0; i < 4; i++) {
            int idx = tid + i * 256;
            int r = idx >> 4, c = idx & 15;
            As[c][r] = A[(long)(bm + r) * lda + (k0 + c)];
            Ws[c][r] = W[(long)(bn + r) * ldw + (k0 + c)];
        }
        __syncthreads();
#pragma unroll
        for (int kk = 0; kk < 16; kk++) {
            const float4 a = *(const float4*)&As[kk][ty * 4];
            const float4 w = *(const float4*)&Ws[kk][tx * 4];
            acc[0][0] += a.x * w.x; acc[0][1] += a.x * w.y; acc[0][2] += a.x * w.z; acc[0][3] += a.x * w.w;
            acc[1][0] += a.y * w.x; acc[1][1] += a.y * w.y; acc[1][2] += a.y * w.z; acc[1][3] += a.y * w.w;
            acc[2][0] += a.z * w.x; acc[2][1] += a.z * w.y; acc[2][2] += a.z * w.z; acc[2][3] += a.z * w.w;
            acc[3][0] += a.w * w.x; acc[3][1] += a.w * w.y; acc[3][2] += a.w * w.z; acc[3][3] += a.w * w.w;
        }
        __syncthreads();
    }

    const int n0 = bn + tx * 4;
    float4 bv = make_float4(0.f, 0.f, 0.f, 0.f);
    if (bias) bv = *(const float4*)&bias[n0];
#pragma unroll
    for (int i = 0; i < 4; i++) {
        const int m = bm + ty * 4 + i;
        float4 r;
        if (rtab) {
            r.x = acc[i][0] * scale + rtab[rp[(n0 + 0) * 256 + m] * 8 + hz];
            r.y = acc[i][1] * scale + rtab[rp[(n0 + 1) * 256 + m] * 8 + hz];
            r.z = acc[i][2] * scale + rtab[rp[(n0 + 2) * 256 + m] * 8 + hz];
            r.w = acc[i][3] * scale + rtab[rp[(n0 + 3) * 256 + m] * 8 + hz];
        } else {
            r.x = (acc[i][0] + bv.x) * scale;
            r.y = (acc[i][1] + bv.y) * scale;
            r.z = (acc[i][2] + bv.z) * scale;
            r.w = (acc[i][3] + bv.w) * scale;
        }
        bf16 t4[4];
        t4[0] = __float2bfloat16(r.x);
        t4[1] = __float2bfloat16(r.y);
        t4[2] = __float2bfloat16(r.z);
        t4[3] = __float2bfloat16(r.w);
        if (rtab) {
            bf16* dst = C + ((long)blockIdx.x * 4 + (tx >> 2)) * 4096
                          + ((long)blockIdx.y * 4 + (ty >> 2)) * 256;
            const int lane2 = (tx & 3) * 16 + ((ty * 4 + i) & 15);
            *(uint2*)&dst[lane2 * 4] = *(uint2*)t4;
        } else {
            *(uint2*)&C[(long)m * ldc + n0] = *(uint2*)t4;
        }
    }
}

// ---------------------------------------------------------------------------
// Setup mega-kernel (role by blockIdx ranges)
// ---------------------------------------------------------------------------
constexpr int RB_A = 10368;
constexpr int RB_B = RB_A + 3456;
constexpr int RB_C = RB_B + 54;
constexpr int RB_D = RB_C + 6144;   // packed: 8192 rows x 192 f32x4 units
constexpr int RB_E = RB_D + 256;
constexpr int RB_F = RB_E + 1152;
constexpr int RB_G = RB_F + 2;

__global__ __launch_bounds__(256) void setup_mega_kernel(
    const int* __restrict__ tokens, const float* __restrict__ embed,
    const float* __restrict__ pos_emb,
    const float* __restrict__ pos_q_w, const float* __restrict__ pos_q_b,
    const float* __restrict__ pos_k_w, const float* __restrict__ pos_k_b,
    const float* __restrict__ pos_ln_g, const float* __restrict__ pos_ln_b,
    const float* __restrict__ Wq, const float* __restrict__ Wk,
    const float* __restrict__ Wv, const float* __restrict__ Wo,
    const float* __restrict__ bq, const float* __restrict__ bk,
    const float* __restrict__ bv,
    bf16* __restrict__ wqkv, bf16* __restrict__ woT, float* __restrict__ bqkv,
    bf16* __restrict__ xb, bf16* __restrict__ wln,
    bf16* __restrict__ wsW, float* __restrict__ wsB, float scale)
{
    const int bid = blockIdx.x, tid = threadIdx.x;

    if (bid < RB_A) {
        const long idx = (long)bid * 256 + tid;
        const long e = idx * 4;
        const int k = (int)(e % 768);
        const long nl = e / 768;
        const int n = (int)(nl % 2304);
        const int l = (int)(nl / 2304);
        const float* src;
        float sc = 1.f;
        if (n < 768)       { src = Wq + ((long)l * 768 + n) * 768; sc = scale; }
        else if (n < 1536) { src = Wk + ((long)l * 768 + (n - 768)) * 768; }
        else               { src = Wv + ((long)l * 768 + (n - 1536)) * 768; }
        const float4 v = *(const float4*)&src[k];
        bf16 tmp[4];
        tmp[0] = __float2bfloat16(v.x * sc);
        tmp[1] = __float2bfloat16(v.y * sc);
        tmp[2] = __float2bfloat16(v.z * sc);
        tmp[3] = __float2bfloat16(v.w * sc);
        *(uint2*)&wqkv[((long)l * 2304 + n) * 768 + k] = *(uint2*)tmp;
    } else if (bid < RB_B) {
        __shared__ float t[32][33];
        const int b2 = bid - RB_A;
        const int l = b2 / 576, r2 = b2 % 576;
        const int c0 = (r2 % 24) * 32, j0 = (r2 / 24) * 32;
        const int tx = tid & 31, ty = tid >> 5;
        const float* src = Wo + (long)l * 768 * 768;
#pragma unroll
        for (int rr = 0; rr < 32; rr += 8)
            t[ty + rr][tx] = src[(long)(c0 + ty + rr) * 768 + j0 + tx];
        __syncthreads();
        bf16* dst = woT + (long)l * 768 * 768;
#pragma unroll
        for (int rr = 0; rr < 32; rr += 8)
            dst[(long)(j0 + ty + rr) * 768 + c0 + tx] = __float2bfloat16(t[tx][ty + rr]);
    } else if (bid < RB_C) {
        const int idx = (bid - RB_B) * 256 + tid;
        if (idx < 6 * 2304) {
            const int n = idx % 2304, l = idx / 2304;
            float v;
            if (n < 768)       v = bq[l * 768 + n] * scale;
            else if (n < 1536) v = bk[l * 768 + (n - 768)];
            else               v = bv[l * 768 + (n - 1536)];
            bqkv[idx] = v;
        }
    } else if (bid < RB_D) {
        const int idx = (bid - RB_C) * 256 + tid;   // < 8192*192
        const int t = idx / 192;
        const int d = idx - t * 192;
        const int tok = tokens[t];
        const float4 v = ((const float4*)(embed + (long)tok * DIM))[d];
        bf16 tmp[4];
        tmp[0] = __float2bfloat16(v.x);
        tmp[1] = __float2bfloat16(v.y);
        tmp[2] = __float2bfloat16(v.z);
        tmp[3] = __float2bfloat16(v.w);
        *(uint2*)&xb[(long)t * DIM + d * 4] = *(uint2*)tmp;
    } else if (bid < RB_E) {
        __shared__ float buf[256];
        const int i = bid - RB_D;
        const float* row = pos_emb + (long)i * DIM;
        float v0 = row[tid], v1 = row[tid + 256], v2 = row[tid + 512];
        buf[tid] = v0 + v1 + v2;
        __syncthreads();
        for (int off = 128; off > 0; off >>= 1) {
            if (tid < off) buf[tid] += buf[tid + off];
            __syncthreads();
        }
        const float mean = buf[0] * (1.f / 768.f);
        __syncthreads();
        const float d0 = v0 - mean, d1 = v1 - mean, d2 = v2 - mean;
        buf[tid] = d0 * d0 + d1 * d1 + d2 * d2;
        __syncthreads();
        for (int off = 128; off > 0; off >>= 1) {
            if (tid < off) buf[tid] += buf[tid + off];
            __syncthreads();
        }
        const float rstd = rsqrtf(buf[0] * (1.f / 768.f) + 1e-5f);
        bf16* wr = wln + (long)i * DIM;
        wr[tid]       = __float2bfloat16(d0 * rstd * pos_ln_g[tid]       + pos_ln_b[tid]);
        wr[tid + 256] = __float2bfloat16(d1 * rstd * pos_ln_g[tid + 256] + pos_ln_b[tid + 256]);
        wr[tid + 512] = __float2bfloat16(d2 * rstd * pos_ln_g[tid + 512] + pos_ln_b[tid + 512]);
    } else if (bid < RB_F) {
        const long idx = (long)(bid - RB_E) * 256 + tid;
        const long e = idx * 4;
        const float4 v = (e < 589824) ? *(const float4*)&pos_q_w[e]
                                      : *(const float4*)&pos_k_w[e - 589824];
        bf16 tmp[4];
        tmp[0] = __float2bfloat16(v.x);
        tmp[1] = __float2bfloat16(v.y);
        tmp[2] = __float2bfloat16(v.z);
        tmp[3] = __float2bfloat16(v.w);
        *(uint2*)&wsW[e] = *(uint2*)tmp;
    } else {
        const int idx = (bid - RB_F) * 256 + tid;
        wsB[idx] = (idx < 768) ? pos_q_b[idx] : pos_k_b[idx - 768];
    }
}

// bf[l][n] = wqkv[l+1][n,:] . bo[l] + bqkv[l+1][n]   (l = 0..4)
__global__ __launch_bounds__(256) void fused_bias_kernel(
    const bf16* __restrict__ wqkv, const float* __restrict__ bo,
    const float* __restrict__ bqkv, float* __restrict__ bf_)
{
    const int l = blockIdx.y;
    const int lane = threadIdx.x & 63, wave = threadIdx.x >> 6;
    const int nloc = wave * 8 + (lane >> 3);
    const int seg = lane & 7;
    const int n = blockIdx.x * 32 + nloc;
    const bf16* wrow = wqkv + ((long)(l + 1) * 2304 + n) * 768 + seg * 96;
    const float* bsrc = bo + (long)l * 768 + seg * 96;
    float s = 0.f;
#pragma unroll
    for (int c8 = 0; c8 < 12; c8++) {
        const short8 w8 = *(const short8*)&wrow[c8 * 8];
#pragma unroll
        for (int e = 0; e < 8; e++) {
            bf16 b;
            *(short*)&b = w8[e];
            s += __bfloat162float(b) * bsrc[c8 * 8 + e];
        }
    }
    s += __shfl_xor(s, 1);
    s += __shfl_xor(s, 2);
    s += __shfl_xor(s, 4);
    if (seg == 0) bf_[l * 2304 + n] = s + bqkv[(l + 1) * 2304 + n];
}

// ---------------------------------------------------------------------------
// bf16 MFMA GEMM: 128x128 tile, BK=64, ping-pong double-buffered LDS.
// ---------------------------------------------------------------------------
#define GEMM_PREF(AS, BS, KB)                                                 \
  {                                                                           \
    _Pragma("unroll")                                                         \
    for (int i = 0; i < 2; i++) {                                             \
      const int u = tid + i * 512;                                            \
      const int r = u >> 3, c = u & 7;                                        \
      const int ca = c ^ (r & 7);                                             \
      ASYNC_COPY16(A + (bm + r) * (long)K + (KB) + ca * 8, &AS[u * 8]);       \
      ASYNC_COPY16(B + (bn + r) * (long)K + (KB) + ca * 8, &BS[u * 8]);       \
    }                                                                         \
  }

#define GEMM_COMPUTE(AS, BS)                                                  \
  {                                                                           \
    _Pragma("unroll")                                                         \
    for (int ks = 0; ks < 2; ks++) {                                          \
      const int cc = ks * 4 + quad;                                           \
      short8 af[4], bfr[2];                                                   \
      _Pragma("unroll")                                                       \
      for (int t = 0; t < 4; t++) {                                           \
        const int ra = wm * 64 + t * 16 + col;                                \
        af[t] = *(const short8*)&AS[ra * 64 + ((cc ^ (ra & 7)) * 8)];         \
      }                                                                       \
      _Pragma("unroll")                                                       \
      for (int t = 0; t < 2; t++) {                                           \
        const int rb = wn * 32 + t * 16 + col;                                \
        bfr[t] = *(const short8*)&BS[rb * 64 + ((cc ^ (rb & 7)) * 8)];        \
      }                                                                       \
      _Pragma("unroll")                                                       \
      for (int tm = 0; tm < 4; tm++)                                          \
        _Pragma("unroll")                                                     \
        for (int tn = 0; tn < 2; tn++)                                        \
          acc[tm][tn] = __builtin_amdgcn_mfma_f32_16x16x32_bf16(af[tm], bfr[tn], acc[tm][tn], 0, 0, 0); \
    }                                                                         \
  }

__global__ __launch_bounds__(512, 4) void gemm_bf16_kernel(
    const bf16* __restrict__ A, const bf16* __restrict__ B,
    const float* __restrict__ bias,
    bf16* __restrict__ Cb, bf16* __restrict__ vTout, float* __restrict__ Cf,
    int N, int K, int swz, long az, long bz, long cz, long biasz, int skipQ)
{
    __shared__ bf16 As0[128 * 64];
    __shared__ bf16 Bs0[128 * 64];
    __shared__ bf16 As1[128 * 64];
    __shared__ bf16 Bs1[128 * 64];

    A += (long)blockIdx.z * az;
    B += (long)blockIdx.z * bz;
    if (Cb) Cb += (long)blockIdx.z * cz;
    if (Cf) Cf += (long)blockIdx.z * cz;
    if (bias) bias += (long)blockIdx.z * biasz;

    const int tid = threadIdx.x;
    const int lane = tid & 63, wave = tid >> 6;   // 8 waves
    const int wm = wave & 1, wn = wave >> 1;      // 2m x 4n

    int bmt, bnt;
    if (swz) {
        const int id = blockIdx.x + gridDim.x * blockIdx.y;
        const int xcd = id & 7, loc = id >> 3;
        bmt = xcd * 8 + (loc & 7);
        bnt = loc >> 3;
    } else {
        bmt = blockIdx.y;
        bnt = blockIdx.x;
    }
    if (skipQ && bnt < 6 && (bmt & 1)) return;

    const long bm = (long)bmt * 128, bn = (long)bnt * 128;
    const int col = lane & 15, quad = lane >> 4;

    f32x4 acc[4][2] = {};

    GEMM_PREF(As0, Bs0, 0);
    for (int kk = 0; kk < K; kk += 128) {
        __syncthreads();
        GEMM_PREF(As1, Bs1, kk + 64);
        GEMM_COMPUTE(As0, Bs0);
        __syncthreads();
        if (kk + 128 < K) GEMM_PREF(As0, Bs0, kk + 128);
        GEMM_COMPUTE(As1, Bs1);
    }

    const bool toVT = (vTout != nullptr) && (bn >= 1536);

    if (toVT) {
        // wave-local 64m x 32n transpose through LDS (4 KB scratch per wave)
        __syncthreads();
        bf16* tb = (wave < 4 ? As0 : Bs0) + (wave & 3) * 2048;
#pragma unroll
        for (int tn = 0; tn < 2; tn++) {
            const int nl = tn * 16 + col;                 // 0..31
            const float bvv = bias[bn + wn * 32 + nl];
#pragma unroll
            for (int tm = 0; tm < 4; tm++) {
                const int mc = tm * 4 + quad;             // 0..15 (4-bf16 m-chunk)
                bf16 t4[4];
#pragma unroll
                for (int r = 0; r < 4; r++)
                    t4[r] = __float2bfloat16(acc[tm][tn][r] + bvv);
                *(uint2*)&tb[(nl * 16 + (mc ^ (nl & 15))) * 4] = *(uint2*)t4;
            }
        }
        const int b_  = (int)((bm + wm * 64) >> 8);
        const int s0  = (int)((bm + wm * 64) & 255);
        const long nb = bn + wn * 32 - 1536;
#pragma unroll
        for (int it2 = 0; it2 < 8; it2++) {
            const int nl = it2 * 4 + quad;                // 0..31
            const uint2 v = *(const uint2*)&tb[(nl * 16 + (col ^ (nl & 15))) * 4];
            *(uint2*)&vTout[((long)b_ * 768 + nb + nl) * 256 + s0 + col * 4] = v;
        }
    } else if (Cf) {
#pragma unroll
        for (int tn = 0; tn < 2; tn++) {
            const long n = bn + wn * 32 + tn * 16 + col;
            const float bvv = bias ? bias[n] : 0.f;
#pragma unroll
            for (int tm = 0; tm < 4; tm++) {
                const long m0 = bm + wm * 64 + tm * 16 + quad * 4;
#pragma unroll
                for (int r = 0; r < 4; r++)
                    Cf[(m0 + r) * N + n] = acc[tm][tn][r] + bvv;
            }
        }
    } else {
#pragma unroll
        for (int tn = 0; tn < 2; tn++) {
            const long n = bn + wn * 32 + tn * 16 + col;
            const float bvv = bias ? bias[n] : 0.f;
#pragma unroll
            for (int tm = 0; tm < 4; tm++) {
                const long m0 = bm + wm * 64 + tm * 16 + quad * 4;
#pragma unroll
                for (int r = 0; r < 4; r++)
                    Cb[(m0 + r) * N + n] = __float2bfloat16(acc[tm][tn][r] + bvv);
            }
        }
    }
}

// ---------------------------------------------------------------------------
// R7: K/V-resident MFMA attention. One block per (b,h): 512 thr / 8 waves,
// K (256x128, 64KB) + V (4x96x64, 48KB) staged ONCE, Ps 128x136 (34KB).
// Two 4-wave teams each process 2 Q-tiles; ONE barrier total (post-stage);
// K/V read-only resident, Ps rows wave-private. nit: #Q-tiles (4 or 1).
// Arithmetic & accumulation order identical to R6 -> absmax bit-identical.
// ---------------------------------------------------------------------------
#define SCORE_R(JC)                                                          \
  { __builtin_amdgcn_s_setprio(1);                                           \
    _Pragma("unroll")                                                        \
    for (int ks = 0; ks < 3; ks++) {                                         \
      _Pragma("unroll")                                                      \
      for (int jt2 = 0; jt2 < 4; jt2++) {                                    \
        const int row = (JC) * 64 + jt2 * 16 + col;                          \
        const int cc = ks * 4 + quad;                                        \
        const short8 bk_ = *(const short8*)&Ks[row * 128 + ((cc ^ (row & 15)) * 8)]; \
        accS[(JC) * 4 + jt2] = __builtin_amdgcn_mfma_f32_16x16x32_bf16(aqv[ks], bk_, accS[(JC) * 4 + jt2], 0, 0, 0); \
      } }                                                                     \
    __builtin_amdgcn_s_setprio(0); }

#define PV_R(KC, PC)                                                         \
  { __builtin_amdgcn_s_setprio(1);                                           \
    _Pragma("unroll")                                                        \
    for (int k2 = 0; k2 < 2; k2++) {                                         \
      const short8 ap = *(const short8*)&Ps[(wave * 16 + col) * PS + (PC) * 64 + k2 * 32 + quad * 8]; \
      _Pragma("unroll")                                                      \
      for (int nt = 0; nt < 6; nt++) {                                       \
        const int row = nt * 16 + col;                                       \
        const int c = k2 * 4 + quad;                                         \
        const short8 bv_ = *(const short8*)&Vs[(KC) * 6144 + row * 64 + ((c ^ (row & 7)) * 8)]; \
        accO[nt] = __builtin_amdgcn_mfma_f32_16x16x32_bf16(ap, bv_, accO[nt], 0, 0, 0); \
      } }                                                                     \
    __builtin_amdgcn_s_setprio(0); }

__global__ __launch_bounds__(512, 2) void attn_mfma_kernel(
    const bf16* __restrict__ qkv, const bf16* __restrict__ vT,
    const bf16* __restrict__ biasTp, bf16* __restrict__ o, int nit)
{
    constexpr int PS = 136;
    __shared__ bf16 Ks[256 * 128];    // 64 KB
    __shared__ bf16 Vs[4 * 96 * 64];  // 48 KB
    __shared__ bf16 Ps[128 * PS];     // 34 KB

    const int blk = blockIdx.x;
    const int h  = blk & 7;           // XCD-affine: one head per XCD
    const int b  = blk >> 3;
    const int tid = threadIdx.x, lane = tid & 63, wave = tid >> 6;
    const int team = wave >> 2, wl = wave & 3;
    const int col = lane & 15, quad = lane >> 4;
    const long rowbase = (long)b * SEQ;

    const bf16* kbase = qkv + rowbase * 2304 + 768 + h * 96;
    const bf16* vbase = vT + ((long)b * 768 + h * 96) * 256;

    // Q fragments for this team's first Q-tile (always loaded; unused if guarded)
    const int it0 = team * 2;
    short8 aq[3];
    {
        const bf16* qrow = qkv + (rowbase + it0 * 64 + wl * 16 + col) * 2304 + h * 96;
#pragma unroll
        for (int ks = 0; ks < 3; ks++)
            aq[ks] = *(const short8*)&qrow[ks * 32 + quad * 8];
    }

    // stage K: 256 rows x 16 swizzled 8-elem chunks (4096 units, 8 rounds)
#pragma unroll
    for (int i = 0; i < 8; i++) {
        const int u = tid + i * 512;
        const int r = u >> 4, pp = u & 15;
        const int c = pp ^ (r & 15);
        ASYNC_COPY16(kbase + (long)r * 2304 + c * 8, &Ks[u * 8]);
    }
    // stage V: 4 chunks x 96 rows x 8 swizzled 8-elem chunks (3072 units, 6 rounds)
#pragma unroll
    for (int i = 0; i < 6; i++) {
        const int u = tid + i * 512;
        const int KC = u / 768;
        const int w = u - KC * 768;
        const int r = w >> 3, pp = w & 7;
        const int c = pp ^ (r & 7);
        ASYNC_COPY16(vbase + r * 256 + KC * 64 + c * 8, &Vs[u * 8]);
    }

    __syncthreads();   // drains vmcnt(0): all K/V staged & visible

    // per-Q-tile body (no barriers inside; Ps rows wave-private)
    auto process = [&](int it, const short8 aqv[3]) {
        f32x4 accS[16] = {};
        SCORE_R(0); SCORE_R(1); SCORE_R(2); SCORE_R(3);

        // lane-coalesced bias (R6 layout), row-owner = wl
        {
            const bf16* bbT = biasTp + ((long)(h * 16 + it * 4 + wl) * 4096) + lane * 4;
#pragma unroll
            for (int jt = 0; jt < 16; jt++) {
                bf16 b4[4];
                *(uint2*)b4 = *(const uint2*)&bbT[jt * 256];
                accS[jt][0] += __bfloat162float(b4[0]);
                accS[jt][1] += __bfloat162float(b4[1]);
                accS[jt][2] += __bfloat162float(b4[2]);
                accS[jt][3] += __bfloat162float(b4[3]);
            }
        }

#pragma unroll
        for (int r = 0; r < 4; r++) {
            float t0 = fmaxf(fmaxf(accS[0][r],  accS[1][r]),  accS[2][r]);
            float t1 = fmaxf(fmaxf(accS[3][r],  accS[4][r]),  accS[5][r]);
            float t2 = fmaxf(fmaxf(accS[6][r],  accS[7][r]),  accS[8][r]);
            float t3 = fmaxf(fmaxf(accS[9][r],  accS[10][r]), accS[11][r]);
            float t4 = fmaxf(fmaxf(accS[12][r], accS[13][r]), accS[14][r]);
            float m  = fmaxf(fmaxf(fmaxf(t0, t1), t2), fmaxf(fmaxf(t3, t4), accS[15][r]));
            for (int d = 1; d < 16; d <<= 1) m = fmaxf(m, __shfl_xor(m, d));
            float s = 0.f;
#pragma unroll
            for (int jt = 0; jt < 16; jt++) {
                const float e = __expf(accS[jt][r] - m);
                accS[jt][r] = e;
                s += e;
            }
            for (int d = 1; d < 16; d <<= 1) s += __shfl_xor(s, d);
            const float inv = __builtin_amdgcn_rcpf(s);
#pragma unroll
            for (int jt = 0; jt < 16; jt++) accS[jt][r] *= inv;
            const int prow = wave * 16 + quad * 4 + r;
#pragma unroll
            for (int jt = 0; jt < 8; jt++)
                Ps[prow * PS + jt * 16 + col] = __float2bfloat16(accS[jt][r]);
        }

        f32x4 accO[6] = {};
        PV_R(0, 0);
        PV_R(1, 1);
        // overwrite wave-private Ps rows with keys 128..255
#pragma unroll
        for (int r = 0; r < 4; r++) {
            const int prow = wave * 16 + quad * 4 + r;
#pragma unroll
            for (int jt = 8; jt < 16; jt++)
                Ps[prow * PS + (jt - 8) * 16 + col] = __float2bfloat16(accS[jt][r]);
        }
        PV_R(2, 0);
        PV_R(3, 1);

#pragma unroll
        for (int nt = 0; nt < 6; nt++)
#pragma unroll
            for (int r = 0; r < 4; r++) {
                const long m = rowbase + it * 64 + wl * 16 + quad * 4 + r;
                o[m * DIM + h * 96 + nt * 16 + col] = __float2bfloat16(accO[nt][r]);
            }
    };

    if (it0 < nit) process(it0, aq);
    const int it1 = it0 + 1;
    if (it1 < nit) {
        short8 aq2[3];
        const bf16* qrow = qkv + (rowbase + it1 * 64 + wl * 16 + col) * 2304 + h * 96;
#pragma unroll
        for (int ks = 0; ks < 3; ks++)
            aq2[ks] = *(const short8*)&qrow[ks * 32 + quad * 8];
        process(it1, aq2);
    }
}

// out[b, ng*32 + tid>>3] = ob[b*256,:] . Wo5[n,:] + bo5[n]
__global__ __launch_bounds__(256) void final_out_kernel(
    const bf16* __restrict__ ob, const float* __restrict__ Wo5,
    const float* __restrict__ bo5, float* __restrict__ out)
{
    __shared__ float os[768];
    const int b = blockIdx.y, ng = blockIdx.x, tid = threadIdx.x;
    const bf16* orow = ob + (long)b * 256 * 768;
    for (int i = tid; i < 768; i += 256) os[i] = __bfloat162float(orow[i]);
    __syncthreads();

    const int n = ng * 32 + (tid >> 3);
    const int seg = tid & 7;
    const float* wrow = Wo5 + (long)n * 768 + seg * 96;
    const float* xs = &os[seg * 96];
    float s = 0.f;
#pragma unroll
    for (int k = 0; k < 96; k += 4) {
        const float4 w = *(const float4*)&wrow[k];
        s += xs[k] * w.x + xs[k + 1] * w.y + xs[k + 2] * w.z + xs[k + 3] * w.w;
    }
    s += __shfl_xor(s, 1);
    s += __shfl_xor(s, 2);
    s += __shfl_xor(s, 4);
    if (seg == 0) out[b * 768 + n] = s + bo5[n];
}

extern "C" void kernel_launch(void* const* d_in, const int* in_sizes, int n_in,
                              void* d_out, int out_size, void* d_ws, size_t ws_size,
                              hipStream_t stream)
{
    const int*   tokens   = (const int*)d_in[0];
    const float* embed    = (const float*)d_in[1];
    const float* pos_emb  = (const float*)d_in[2];
    const float* pos_q_w  = (const float*)d_in[3];
    const float* pos_q_b  = (const float*)d_in[4];
    const float* pos_k_w  = (const float*)d_in[5];
    const float* pos_k_b  = (const float*)d_in[6];
    const float* pos_ln_g = (const float*)d_in[7];
    const float* pos_ln_b = (const float*)d_in[8];
    const float* rel_tab  = (const float*)d_in[9];
    const int*   rp       = (const int*)d_in[10];
    const float* Wq = (const float*)d_in[11];
    const float* bq = (const float*)d_in[12];
    const float* Wk = (const float*)d_in[13];
    const float* bk = (const float*)d_in[14];
    const float* Wv = (const float*)d_in[15];
    const float* bv = (const float*)d_in[16];
    const float* Wo = (const float*)d_in[17];
    const float* bo = (const float*)d_in[18];
    float* out = (float*)d_out;

    char* p = (char*)d_ws;
    auto alloc = [&](size_t bytes) -> char* {
        char* r = p;
        p += (bytes + 255) & ~(size_t)255;
        return r;
    };
    const long NT = 32L * SEQ;  // 8192

    bf16*  biasT = (bf16*) alloc(8L * SEQ * SEQ * 2);       // lane-layout bf16
    bf16*  wlnb  = (bf16*) alloc((long)SEQ * DIM * 2);
    float* pqk   = (float*)alloc(2L * SEQ * DIM * 4);       // pq | pk (f32)
    bf16*  wsWb  = (bf16*) alloc(2L * 768 * 768 * 2);       // posq_w | posk_w bf16
    float* wsB   = (float*)alloc(2L * 768 * 4);
    bf16*  xb    = (bf16*) alloc(NT * DIM * 2);
    bf16*  qkv   = (bf16*) alloc(NT * 2304 * 2);
    bf16*  vT    = (bf16*) alloc(NT * DIM * 2);             // [32][768][256]
    bf16*  ob    = (bf16*) alloc(NT * DIM * 2);
    bf16*  wqkv  = (bf16*) alloc(6L * 2304 * 768 * 2);
    bf16*  woT   = (bf16*) alloc(6L * 768 * 768 * 2);
    bf16*  wf    = (bf16*) alloc(5L * 2304 * 768 * 2);
    float* bqkv  = (float*)alloc(6L * 2304 * 4);
    float* bfus  = (float*)alloc(5L * 2304 * 4);

    const float SCALE = 0.07216878364870322f;   // (HD*2)^-0.5

    // ---- all independent setup in ONE launch ----
    setup_mega_kernel<<<RB_G, 256, 0, stream>>>(
        tokens, embed, pos_emb, pos_q_w, pos_q_b, pos_k_w, pos_k_b,
        pos_ln_g, pos_ln_b, Wq, Wk, Wv, Wo, bq, bk, bv,
        wqkv, woT, bqkv, xb, wlnb, wsWb, wsB, SCALE);

    // Wf_l = Wqkv_{l+1} . Wo_l  (batched, z = l)
    gemm_bf16_kernel<<<dim3(6, 18, 5), 512, 0, stream>>>(
        wqkv + 2304L * 768, woT, nullptr, wf, nullptr, nullptr, 768, 768, 0,
        2304L * 768, 768L * 768, 2304L * 768, 0, 0);
    fused_bias_kernel<<<dim3(72, 5), 256, 0, stream>>>(wqkv, bo, bqkv, bfus);

    // pos projections pq|pk via MFMA (bf16 in, f32 out), z = {q, k}
    gemm_bf16_kernel<<<dim3(6, 2, 2), 512, 0, stream>>>(
        wlnb, wsWb, wsB, nullptr, nullptr, pqk, 768, 768, 0,
        0, 768L * 768, (long)SEQ * DIM, 768, 0);
    // biasTp (lane layout) = SCALE * (pk_j . pq_i) + rel[i,j,h]
    gemm_kernel<<<dim3(4, 4, NH), 256, 0, stream>>>(
        pqk + (long)SEQ * DIM, DIM, HD, pqk, DIM, HD, nullptr, 0,
        biasT, SEQ, (long)SEQ * SEQ, SEQ, SEQ, HD, SCALE, rp, rel_tab);

    // ---- layer pipeline ----
    gemm_bf16_kernel<<<dim3(18, 64, 1), 512, 0, stream>>>(
        xb, wqkv, bqkv, qkv, vT, nullptr, 2304, 768, 1, 0, 0, 0, 0, 0);
    for (int l = 0; l < 5; l++) {
        attn_mfma_kernel<<<256, 512, 0, stream>>>(qkv, vT, biasT, ob, 4);
        gemm_bf16_kernel<<<dim3(18, 64, 1), 512, 0, stream>>>(
            ob, wf + (long)l * 2304 * 768, bfus + (long)l * 2304, qkv, vT, nullptr,
            2304, 768, 1, 0, 0, 0, 0, (l == 4) ? 1 : 0);
    }
    attn_mfma_kernel<<<256, 512, 0, stream>>>(qkv, vT, biasT, ob, 1);
    final_out_kernel<<<dim3(24, 32), 256, 0, stream>>>(ob, Wo + 5L * 768 * 768, bo + 5L * 768, out);
}